// Round 17
// baseline (466.293 us; speedup 1.0000x reference)
//
#include <hip/hip_runtime.h>
#include <hip/hip_bf16.h>

// DNRI step: B=32, N=100, D=4, H=256, K=4 (skip type 0), E=9900.
// R16: revert R15 (fused pipeline: 138us > serial 98us). R11 base +
// (a) k2a writes m1G PRE-SWIZZLED (XOR on global write, stays coalesced),
// (b) k2b stages via global_load_lds width=16 (linear LDS dest, swizzled
//     source per rule #21; zero VGPR cost, async DMA),
// (c) k2b processes 2 tiles/block (grid 1600): tile1's DMA issued after
//     barrier-1, lands during tile0's GEMM -> stage fully hidden.

typedef __attribute__((ext_vector_type(4))) float f32x4;
typedef __attribute__((ext_vector_type(8))) short s16x8;
typedef __attribute__((ext_vector_type(4))) unsigned short u16x4;
typedef __attribute__((ext_vector_type(4))) unsigned int u32x4;
typedef __attribute__((ext_vector_type(2))) unsigned int u32x2;

#define DEV static __device__ __forceinline__

DEV unsigned short f2bf(float f) {
  unsigned int u = __builtin_bit_cast(unsigned int, f);
  u += 0x7fffu + ((u >> 16) & 1u);   // RNE
  return (unsigned short)(u >> 16);
}
DEV float bf2f(unsigned short h) {
  unsigned int u = ((unsigned int)h) << 16;
  return __builtin_bit_cast(float, u);
}
DEV float bflo(unsigned int u) { return __builtin_bit_cast(float, u << 16); }
DEV float bfhi(unsigned int u) { return __builtin_bit_cast(float, u & 0xffff0000u); }
DEV float exp2_fast(float x) { return __builtin_amdgcn_exp2f(x); }
DEV float tanh_fast(float x) {
  float e = exp2_fast(x * 2.885390082f);            // exp(2x)
  return 1.f - 2.f * __builtin_amdgcn_rcpf(e + 1.f);
}
DEV float sigmoid_fast(float x) {
  return __builtin_amdgcn_rcpf(1.f + exp2_fast(-1.442695041f * x));
}
DEV unsigned int pk_fp8x4(float a, float b, float c, float d) {
  int v = __builtin_amdgcn_cvt_pk_fp8_f32(a, b, 0, false);   // bytes 0,1
  v = __builtin_amdgcn_cvt_pk_fp8_f32(c, d, v, true);        // bytes 2,3
  return (unsigned int)v;
}
// async global->LDS DMA, 16B per lane; LDS dest = base + lane*16 (wave-uniform base)
DEV void gload_lds16(const unsigned char* g, unsigned char* l) {
  __builtin_amdgcn_global_load_lds(
      (const __attribute__((address_space(1))) void*)g,
      (__attribute__((address_space(3))) void*)l, 16, 0, 0);
}

// ---- LDS staging: 64 rows x 256 bf16, XOR-swizzled ----
DEV void stage_bf16_64(const unsigned short* __restrict__ src, unsigned char* smem, int tid) {
#pragma unroll
  for (int j = 0; j < 8; ++j) {
    int c = tid + 256 * j;
    int s = c >> 5, hc = c & 31;
    s16x8 v = *reinterpret_cast<const s16x8*>(src + s * 256 + hc * 8);
    int byte = (s * 512 + hc * 16) ^ ((s & 7) << 4);
    *reinterpret_cast<s16x8*>(smem + byte) = v;
  }
}
DEV void stage_f32_64(const float* __restrict__ src, unsigned char* smem, int tid) {
#pragma unroll
  for (int j = 0; j < 8; ++j) {
    int c = tid + 256 * j;
    int s = c >> 5, hc = c & 31;
    const float* p = src + s * 256 + hc * 8;
    f32x4 v0 = *reinterpret_cast<const f32x4*>(p);
    f32x4 v1 = *reinterpret_cast<const f32x4*>(p + 4);
    s16x8 o;
#pragma unroll
    for (int i = 0; i < 4; ++i) { o[i] = (short)f2bf(v0[i]); o[4 + i] = (short)f2bf(v1[i]); }
    int byte = (s * 512 + hc * 16) ^ ((s & 7) << 4);
    *reinterpret_cast<s16x8*>(smem + byte) = o;
  }
}
// staging that sums three f32 partial buffers -> bf16 swizzled LDS
DEV void stage_sum3_f32(const float* __restrict__ sa, const float* __restrict__ sb,
                        const float* __restrict__ sc, unsigned char* smem, int tid) {
#pragma unroll
  for (int j = 0; j < 8; ++j) {
    int c = tid + 256 * j;
    int s = c >> 5, hc = c & 31;
    int o4 = s * 256 + hc * 8;
    f32x4 a0 = *reinterpret_cast<const f32x4*>(sa + o4);
    f32x4 a1 = *reinterpret_cast<const f32x4*>(sa + o4 + 4);
    f32x4 b0 = *reinterpret_cast<const f32x4*>(sb + o4);
    f32x4 b1 = *reinterpret_cast<const f32x4*>(sb + o4 + 4);
    f32x4 c0 = *reinterpret_cast<const f32x4*>(sc + o4);
    f32x4 c1 = *reinterpret_cast<const f32x4*>(sc + o4 + 4);
    s16x8 o;
#pragma unroll
    for (int i = 0; i < 4; ++i) {
      o[i] = (short)f2bf(a0[i] + b0[i] + c0[i]);
      o[4 + i] = (short)f2bf(a1[i] + b1[i] + c1[i]);
    }
    int byte = (s * 512 + hc * 16) ^ ((s & 7) << 4);
    *reinterpret_cast<s16x8*>(smem + byte) = o;
  }
}

// ---- bf16 MFMA tile helper (A in swizzled LDS, B^T [n][k] bf16 in global) ----
template<int MF>
DEV void gemm_lds_tile(const unsigned char* smemA, const unsigned short* __restrict__ B,
                       int nb, int lane, f32x4 acc[][4]) {
  int li = lane & 15, lg = lane >> 4;
#pragma unroll
  for (int kk = 0; kk < 8; ++kk) {
    int kb = kk * 32 + lg * 8;
    s16x8 a[MF];
#pragma unroll
    for (int m = 0; m < MF; ++m) {
      int row = m * 16 + li;
      int byte = (row * 512 + kb * 2) ^ ((row & 7) << 4);
      a[m] = *reinterpret_cast<const s16x8*>(smemA + byte);
    }
#pragma unroll
    for (int n = 0; n < 4; ++n) {
      int col = nb + n * 16 + li;
      s16x8 bf = *reinterpret_cast<const s16x8*>(B + col * 256 + kb);
#pragma unroll
      for (int m = 0; m < MF; ++m)
        acc[m][n] = __builtin_amdgcn_mfma_f32_16x16x32_bf16(a[m], bf, acc[m][n], 0, 0, 0);
    }
  }
}

// ---- K0: bf16 transposes (W1a/W1b/Wh-family) ----
__global__ __launch_bounds__(256) void k0_pack(
    const float* __restrict__ msg_W1,
    const float* __restrict__ Whr, const float* __restrict__ Whi, const float* __restrict__ Whh,
    const float* __restrict__ Wo1, const float* __restrict__ Wo2,
    unsigned short* __restrict__ W1aT, unsigned short* __restrict__ W1bT,
    unsigned short* __restrict__ WhT) {
  int g = blockIdx.x * 256 + threadIdx.x;
  if (g < 196608) {               // W1aT[ti][n][k] = msg_W1[ti+1][k][n]
    int ti = g >> 16, rem = g & 65535, n = rem >> 8, k = rem & 255;
    W1aT[g] = f2bf(msg_W1[((ti + 1) * 512 + k) * 256 + n]);
  } else if (g < 393216) {        // W1bT[ti][n][k] = msg_W1[ti+1][256+k][n]
    int h = g - 196608; int ti = h >> 16, rem = h & 65535, n = rem >> 8, k = rem & 255;
    W1bT[h] = f2bf(msg_W1[((ti + 1) * 512 + 256 + k) * 256 + n]);
  } else if (g < 720896) {        // WhT: {Whr,Whi,Whh,Wo1,Wo2}^T
    int h = g - 393216; int mi = h >> 16, rem = h & 65535, n = rem >> 8, k = rem & 255;
    const float* s = mi == 0 ? Whr : mi == 1 ? Whi : mi == 2 ? Whh : mi == 3 ? Wo1 : Wo2;
    WhT[h] = f2bf(s[k * 256 + n]);
  }
}

// ---- K0q: W2 -> fp8 e4m3, layout [ti][col][k] (1B/elem) ----
__global__ __launch_bounds__(256) void k0_quant(
    const float* __restrict__ msg_W2, unsigned short* __restrict__ W2Q) {
  int g = blockIdx.x * 256 + threadIdx.x;          // 98304 = 3*256*128
  int ti = g >> 15, rem = g & 32767, col = rem >> 7, k2 = rem & 127;
  int k = k2 * 2;
  const float* src = msg_W2 + (size_t)(ti + 1) * 65536;
  float a = src[k * 256 + col], b = src[(k + 1) * 256 + col];
  int v = __builtin_amdgcn_cvt_pk_fp8_f32(a, b, 0, false);
  W2Q[g] = (unsigned short)(v & 0xffff);
}

// ---- Xpre[row][3*256] = inputs @ [Wir|Wii|Win] + biases ----
__global__ __launch_bounds__(256) void k_xpre(
    const float* __restrict__ inputs, const float* __restrict__ Wir, const float* __restrict__ bir,
    const float* __restrict__ Wii, const float* __restrict__ bii,
    const float* __restrict__ Win, const float* __restrict__ bin_, float* __restrict__ Xpre) {
  int g = blockIdx.x * 256 + threadIdx.x;   // 3200*768 exact
  int row = g / 768, c = g % 768, which = c >> 8, col = c & 255;
  const float* W = which == 0 ? Wir : which == 1 ? Wii : Win;
  const float* bb = which == 0 ? bir : which == 1 ? bii : bin_;
  const float* inp = inputs + row * 4;
  float s = bb[col];
#pragma unroll
  for (int d = 0; d < 4; ++d) s += inp[d] * W[d * 256 + col];
  Xpre[g] = s;
}

// ---- K1: Ha[ti] = hidden@W1a+b1 (bf16), Hb[ti] = hidden@W1b ----
__global__ __launch_bounds__(256) void k1_nodepre(
    const float* __restrict__ hidden, const float* __restrict__ msg_b1,
    const unsigned short* __restrict__ W1aT, const unsigned short* __restrict__ W1bT,
    unsigned short* __restrict__ Ha, unsigned short* __restrict__ Hb) {
  __shared__ alignas(16) unsigned char smem[32768];
  int tid = threadIdx.x, lane = tid & 63, wv = tid >> 6;
  int mt = blockIdx.x, g = blockIdx.y;
  stage_f32_64(hidden + (size_t)mt * 64 * 256, smem, tid);
  __syncthreads();
  int ti = g < 3 ? g : g - 3;
  const unsigned short* Bp = (g < 3 ? W1aT : W1bT) + ti * 65536;
  f32x4 zz = {0.f, 0.f, 0.f, 0.f};
  f32x4 acc[4][4];
#pragma unroll
  for (int m = 0; m < 4; ++m)
#pragma unroll
    for (int n = 0; n < 4; ++n) acc[m][n] = zz;
  gemm_lds_tile<4>(smem, Bp, wv * 64, lane, acc);
  unsigned short* dst = (g < 3 ? Ha : Hb) + (size_t)ti * 819200 + (size_t)mt * 64 * 256;
  int li = lane & 15, lg = lane >> 4;
#pragma unroll
  for (int n = 0; n < 4; ++n) {
    int col = wv * 64 + n * 16 + li;
    float bias = g < 3 ? msg_b1[(ti + 1) * 256 + col] : 0.f;
#pragma unroll
    for (int m = 0; m < 4; ++m)
#pragma unroll
      for (int q = 0; q < 4; ++q) {
        int row = m * 16 + lg * 4 + q;
        dst[row * 256 + col] = f2bf(acc[m][n][q] + bias);
      }
  }
}

// ---- K2a: streaming build of one type-slice of m1 (fp8, PRE-SWIZZLED) ----
// grid 3200 (b,r); no LDS, no barriers. m1G[bid] holds 28672B whose linear
// layout equals the swizzled-LDS image k2b reads (rule #21 both-sides).
__global__ __launch_bounds__(256) void k2a_build(
    const unsigned short* __restrict__ Ha, const unsigned short* __restrict__ Hb,
    unsigned char* __restrict__ m1G, int ti) {
  int tid = threadIdx.x;
  int bid0 = blockIdx.x;
  int bid = (bid0 & 7) * 400 + (bid0 >> 3);   // XCD-contiguous (3200 = 8*400)
  int b = bid / 100, r = bid % 100;
  int hc = tid & 31, srow0 = tid >> 5;

  u32x4 hau = *reinterpret_cast<const u32x4*>(
      Ha + ((size_t)ti * 3200 + b * 100 + r) * 256 + hc * 8);
  float ha_f[8];
#pragma unroll
  for (int i = 0; i < 4; ++i) { ha_f[2 * i] = bflo(hau[i]); ha_f[2 * i + 1] = bfhi(hau[i]); }
  const unsigned short* HbB = Hb + ((size_t)ti * 3200 + b * 100) * 256;
  unsigned char* dst = m1G + (size_t)bid * 28672;
#pragma unroll
  for (int j = 0; j < 14; ++j) {
    int s = srow0 + 8 * j;
    u32x2 o = {0u, 0u};
    if (s < 99) {
      int snode = s + (s >= r ? 1 : 0);
      u32x4 hb = *reinterpret_cast<const u32x4*>(HbB + snode * 256 + hc * 8);
      float t[8];
#pragma unroll
      for (int i = 0; i < 4; ++i) {
        t[2 * i] = tanh_fast(ha_f[2 * i] + bflo(hb[i]));
        t[2 * i + 1] = tanh_fast(ha_f[2 * i + 1] + bfhi(hb[i]));
      }
      o[0] = pk_fp8x4(t[0], t[1], t[2], t[3]);
      o[1] = pk_fp8x4(t[4], t[5], t[6], t[7]);
    }
    int byte = (s * 256 + hc * 8) ^ ((s & 7) << 4);   // pre-swizzle on global write
    *reinterpret_cast<u32x2*>(dst + byte) = o;
  }
}

// ---- K2b helpers ----
DEV float k2b_loadw(const float* __restrict__ edges, int b, int r, int ti, int tid) {
  float w0 = 0.f;
  if (tid < 99) {
    int snode = tid + (tid >= r ? 1 : 0);
    int e = snode * 99 + r - (r > snode ? 1 : 0);
    w0 = edges[(size_t)(b * 9900 + e) * 4 + (ti + 1)] * (1.f / 297.f);
  }
  return w0;
}
// fp8 GEMM (2 passes acc[7][2]) + tanh epilogue + shuffle reduce -> agg_dst
DEV void k2b_compute(const unsigned char* __restrict__ buf,
                     const unsigned char* __restrict__ Bq,
                     const float* __restrict__ w_s, const float b2r[4],
                     float* __restrict__ agg_dst, int tid) {
  int lane = tid & 63, wv = tid >> 6;
  int li = lane & 15, lg = lane >> 4;
  f32x4 zz = {0.f, 0.f, 0.f, 0.f};
  float aggacc[4] = {0.f, 0.f, 0.f, 0.f};
#pragma unroll
  for (int p = 0; p < 2; ++p) {
    f32x4 acc[7][2];
#pragma unroll
    for (int m = 0; m < 7; ++m) { acc[m][0] = zz; acc[m][1] = zz; }
#pragma unroll
    for (int kk = 0; kk < 8; ++kk) {
      int ko = kk * 32 + lg * 8;
      long a[7];
#pragma unroll
      for (int m = 0; m < 7; ++m) {
        int row = m * 16 + li;
        int byte = (row * 256 + ko) ^ ((row & 7) << 4);
        a[m] = *reinterpret_cast<const long*>(buf + byte);
      }
#pragma unroll
      for (int n = 0; n < 2; ++n) {
        int col = wv * 64 + p * 32 + n * 16 + li;
        long bq = *reinterpret_cast<const long*>(Bq + col * 256 + ko);
#pragma unroll
        for (int m = 0; m < 7; ++m)
          acc[m][n] = __builtin_amdgcn_mfma_f32_16x16x32_fp8_fp8(a[m], bq, acc[m][n], 0, 0, 0);
      }
    }
#pragma unroll
    for (int n = 0; n < 2; ++n) {
      float b2v = b2r[p * 2 + n];
      float pa = 0.f;
#pragma unroll
      for (int m = 0; m < 7; ++m) {
        f32x4 wf = *reinterpret_cast<const f32x4*>(w_s + m * 16 + lg * 4);
#pragma unroll
        for (int q = 0; q < 4; ++q)
          pa += tanh_fast(acc[m][n][q] + b2v) * wf[q];
      }
      aggacc[p * 2 + n] += pa;
    }
  }
#pragma unroll
  for (int n = 0; n < 4; ++n) {
    float v = aggacc[n];
    v += __shfl_xor(v, 16);
    v += __shfl_xor(v, 32);
    if (lane < 16) agg_dst[wv * 64 + n * 16 + lane] = v;
  }
}

// ---- K2b: 2 tiles/block, DMA-staged double buffer ----
// grid 1600; tiles tile0 = swz(bid0) in [0,1600), tile1 = tile0 + 1600.
// LDS: buf0 @0 (28672) | buf1 @28672 | w[2][112] f32 @57344 | agg[2][256] f32 @58240
__global__ __launch_bounds__(256) void k2b_gemm(
    const float* __restrict__ edges, const float* __restrict__ msg_b2,
    const unsigned char* __restrict__ m1G, const unsigned char* __restrict__ W2Q,
    float* __restrict__ pagg, int ti) {
  __shared__ alignas(16) unsigned char smem[60288];
  float* w_s = (float*)(smem + 57344);
  float* agg_s = (float*)(smem + 58240);
  int tid = threadIdx.x, lane = tid & 63, wv = tid >> 6;
  int li = lane & 15;
  int bid0 = blockIdx.x;
  int tile0 = (bid0 & 7) * 200 + (bid0 >> 3);   // XCD-contiguous (1600 = 8*200)
  int tile1 = tile0 + 1600;
  int b0 = tile0 / 100, r0 = tile0 % 100;
  int b1 = tile1 / 100, r1 = tile1 % 100;

  float b2r[4];
#pragma unroll
  for (int n = 0; n < 4; ++n)
    b2r[n] = msg_b2[(ti + 1) * 256 + wv * 64 + n * 16 + li];

  // stage tile0 via async DMA (linear LDS dest; source pre-swizzled by k2a)
  const unsigned char* src0 = m1G + (size_t)tile0 * 28672;
#pragma unroll
  for (int j = 0; j < 7; ++j) {
    int chunk = wv * 7 + j;
    gload_lds16(src0 + chunk * 1024 + lane * 16, smem + chunk * 1024);
  }
  {
    float w0 = k2b_loadw(edges, b0, r0, ti, tid);
    if (tid < 112) w_s[tid] = w0;
  }
  __syncthreads();   // drains DMA (vmcnt) + w_s visible

  const unsigned char* Bq = W2Q + (size_t)ti * 65536;

  // issue tile1 DMA now — lands while tile0 computes
  const unsigned char* src1 = m1G + (size_t)tile1 * 28672;
#pragma unroll
  for (int j = 0; j < 7; ++j) {
    int chunk = wv * 7 + j;
    gload_lds16(src1 + chunk * 1024 + lane * 16, smem + 28672 + chunk * 1024);
  }
  {
    float w1 = k2b_loadw(edges, b1, r1, ti, tid);
    if (tid < 112) w_s[112 + tid] = w1;
  }

  // compute tile0
  k2b_compute(smem, Bq, w_s, b2r, agg_s, tid);
  __syncthreads();   // drains tile1 DMA (already landed) + agg_s/w_s2 visible
  pagg[(size_t)ti * 819200 + (size_t)tile0 * 256 + tid] = agg_s[tid];

  // compute tile1
  k2b_compute(smem + 28672, Bq, w_s + 112, b2r, agg_s + 256, tid);
  __syncthreads();
  pagg[(size_t)ti * 819200 + (size_t)tile1 * 256 + tid] = agg_s[256 + tid];
}

// ---- K3: RIH[y] = (pagg0+pagg1+pagg2) @ {Whr,Whi,Whh}[y] (f32 out) ----
__global__ __launch_bounds__(256) void k3_gemm(
    const float* __restrict__ pagg, const unsigned short* __restrict__ WhT,
    float* __restrict__ RIH) {
  __shared__ alignas(16) unsigned char smem[32768];
  int tid = threadIdx.x, lane = tid & 63, wv = tid >> 6;
  int mt = blockIdx.x, y = blockIdx.y;
  size_t base = (size_t)mt * 64 * 256;
  stage_sum3_f32(pagg + base, pagg + 819200 + base, pagg + 1638400 + base, smem, tid);
  __syncthreads();
  f32x4 zz = {0.f, 0.f, 0.f, 0.f};
  f32x4 acc[4][4];
#pragma unroll
  for (int m = 0; m < 4; ++m)
#pragma unroll
    for (int n = 0; n < 4; ++n) acc[m][n] = zz;
  gemm_lds_tile<4>(smem, WhT + y * 65536, wv * 64, lane, acc);
  float* dst = RIH + (size_t)y * 819200 + base;
  int li = lane & 15, lg = lane >> 4;
#pragma unroll
  for (int n = 0; n < 4; ++n) {
    int col = wv * 64 + n * 16 + li;
#pragma unroll
    for (int m = 0; m < 4; ++m)
#pragma unroll
      for (int q = 0; q < 4; ++q)
        dst[(m * 16 + lg * 4 + q) * 256 + col] = acc[m][n][q];
  }
}

// ---- K4: elementwise GRU combine -> hidden_new ----
__global__ __launch_bounds__(256) void k4_gru(
    const float* __restrict__ Xpre, const float* __restrict__ RIH,
    const float* __restrict__ hidden, float* __restrict__ out, unsigned short* __restrict__ hnewbf) {
  int idx = blockIdx.x * 256 + threadIdx.x;
  int row = idx >> 8, col = idx & 255;
  float xr = Xpre[row * 768 + col];
  float xi = Xpre[row * 768 + 256 + col];
  float xn = Xpre[row * 768 + 512 + col];
  float rr = sigmoid_fast(xr + RIH[idx]);
  float ig = sigmoid_fast(xi + RIH[819200 + idx]);
  float nn = tanh_fast(xn + rr * RIH[1638400 + idx]);
  float hn = (1.f - ig) * nn + ig * hidden[idx];
  out[12800 + idx] = hn;
  hnewbf[idx] = f2bf(hn);
}

// ---- K5/K6: dst = relu(A @ WT + bias) (bf16) ----
__global__ __launch_bounds__(256) void k_mlp(
    const unsigned short* __restrict__ A, const unsigned short* __restrict__ WT,
    const float* __restrict__ bias, unsigned short* __restrict__ dst) {
  __shared__ alignas(16) unsigned char smem[32768];
  int tid = threadIdx.x, lane = tid & 63, wv = tid >> 6;
  int mt = blockIdx.x;
  stage_bf16_64(A + (size_t)mt * 64 * 256, smem, tid);
  __syncthreads();
  f32x4 zz = {0.f, 0.f, 0.f, 0.f};
  f32x4 acc[4][4];
#pragma unroll
  for (int m = 0; m < 4; ++m)
#pragma unroll
    for (int n = 0; n < 4; ++n) acc[m][n] = zz;
  gemm_lds_tile<4>(smem, WT, wv * 64, lane, acc);
  unsigned short* d = dst + (size_t)mt * 64 * 256;
  int li = lane & 15, lg = lane >> 4;
#pragma unroll
  for (int n = 0; n < 4; ++n) {
    int col = wv * 64 + n * 16 + li;
    float bv = bias[col];
#pragma unroll
    for (int m = 0; m < 4; ++m)
#pragma unroll
      for (int q = 0; q < 4; ++q) {
        float v = fmaxf(acc[m][n][q] + bv, 0.f);
        d[(m * 16 + lg * 4 + q) * 256 + col] = f2bf(v);
      }
  }
}

// ---- K7: pred = inputs + pred2 @ Wo3 + bo3 ----
__global__ __launch_bounds__(64) void k7_out(
    const unsigned short* __restrict__ pred2, const float* __restrict__ Wo3,
    const float* __restrict__ bo3, const float* __restrict__ inputs, float* __restrict__ out) {
  int row = blockIdx.x, lane = threadIdx.x;
  u16x4 p = *reinterpret_cast<const u16x4*>(pred2 + (size_t)row * 256 + lane * 4);
  float s0 = 0.f, s1 = 0.f, s2 = 0.f, s3 = 0.f;
#pragma unroll
  for (int j = 0; j < 4; ++j) {
    float pv = bf2f(p[j]);
    const float* wr = Wo3 + (lane * 4 + j) * 4;
    s0 += pv * wr[0]; s1 += pv * wr[1]; s2 += pv * wr[2]; s3 += pv * wr[3];
  }
#pragma unroll
  for (int off = 32; off >= 1; off >>= 1) {
    s0 += __shfl_xor(s0, off); s1 += __shfl_xor(s1, off);
    s2 += __shfl_xor(s2, off); s3 += __shfl_xor(s3, off);
  }
  if (lane == 0) {
    out[row * 4 + 0] = inputs[row * 4 + 0] + s0 + bo3[0];
    out[row * 4 + 1] = inputs[row * 4 + 1] + s1 + bo3[1];
    out[row * 4 + 2] = inputs[row * 4 + 2] + s2 + bo3[2];
    out[row * 4 + 3] = inputs[row * 4 + 3] + s3 + bo3[3];
  }
}

extern "C" void kernel_launch(void* const* d_in, const int* in_sizes, int n_in,
                              void* d_out, int out_size, void* d_ws, size_t ws_size,
                              hipStream_t stream) {
  const float* inputs = (const float*)d_in[0];
  const float* hidden = (const float*)d_in[1];
  const float* edges  = (const float*)d_in[2];
  const float* msg_W1 = (const float*)d_in[3];
  const float* msg_b1 = (const float*)d_in[4];
  const float* msg_W2 = (const float*)d_in[5];
  const float* msg_b2 = (const float*)d_in[6];
  const float* Whr = (const float*)d_in[7];
  const float* Whi = (const float*)d_in[8];
  const float* Whh = (const float*)d_in[9];
  const float* Wir = (const float*)d_in[10];
  const float* bir = (const float*)d_in[11];
  const float* Wii = (const float*)d_in[12];
  const float* bii = (const float*)d_in[13];
  const float* Win = (const float*)d_in[14];
  const float* bin_ = (const float*)d_in[15];
  const float* Wo1 = (const float*)d_in[16];
  const float* bo1 = (const float*)d_in[17];
  const float* Wo2 = (const float*)d_in[18];
  const float* bo2 = (const float*)d_in[19];
  const float* Wo3 = (const float*)d_in[20];
  const float* bo3 = (const float*)d_in[21];
  float* out = (float*)d_out;

  char* ws = (char*)d_ws;
  size_t off = 0;
  auto take = [&](size_t bytes) -> char* {
    char* p = ws + off;
    off += (bytes + 511) & ~(size_t)511;
    return p;
  };
  unsigned short* W1aT = (unsigned short*)take(196608 * 2);
  unsigned short* W1bT = (unsigned short*)take(196608 * 2);
  unsigned short* W2Q  = (unsigned short*)take(196608);      // fp8 [3][256][256]
  unsigned short* WhT  = (unsigned short*)take(327680 * 2);  // WhrT|WhiT|WhhT|Wo1T|Wo2T
  unsigned short* Ha   = (unsigned short*)take(2457600 * 2); // [3][3200][256]
  unsigned short* Hb   = (unsigned short*)take(2457600 * 2);
  float* pagg = (float*)take(3 * 819200 * 4);                // [3][3200][256] partial agg
  unsigned char* m1G = (unsigned char*)take((size_t)3200 * 28672); // one ti slice, 91.75MB
  float* Xpre = (float*)take(2457600 * 4);                   // [3200][768]
  float* RIH  = (float*)take(2457600 * 4);                   // [3][3200][256]
  unsigned short* hnewbf = (unsigned short*)take(819200 * 2);
  unsigned short* pred1  = (unsigned short*)take(819200 * 2);
  unsigned short* pred2  = (unsigned short*)take(819200 * 2);

  k0_pack<<<2816, 256, 0, stream>>>(msg_W1, Whr, Whi, Whh, Wo1, Wo2, W1aT, W1bT, WhT);
  k0_quant<<<384, 256, 0, stream>>>(msg_W2, W2Q);
  k_xpre<<<9600, 256, 0, stream>>>(inputs, Wir, bir, Wii, bii, Win, bin_, Xpre);
  k1_nodepre<<<dim3(50, 6), 256, 0, stream>>>(hidden, msg_b1, W1aT, W1bT, Ha, Hb);
  for (int ti = 0; ti < 3; ++ti) {
    k2a_build<<<3200, 256, 0, stream>>>(Ha, Hb, m1G, ti);
    k2b_gemm<<<1600, 256, 0, stream>>>(edges, msg_b2, m1G,
                                       (const unsigned char*)W2Q, pagg, ti);
  }
  k3_gemm<<<dim3(50, 3), 256, 0, stream>>>(pagg, WhT, RIH);
  k4_gru<<<3200, 256, 0, stream>>>(Xpre, RIH, hidden, out, hnewbf);
  k_mlp<<<50, 256, 0, stream>>>(hnewbf, WhT + 196608, bo1, pred1);
  k_mlp<<<50, 256, 0, stream>>>(pred1, WhT + 262144, bo2, pred2);
  k7_out<<<3200, 64, 0, stream>>>(pred2, Wo3, bo3, inputs, out);
}

// Round 18
// 356.310 us; speedup vs baseline: 1.3087x; 1.3087x over previous
//
#include <hip/hip_runtime.h>
#include <hip/hip_bf16.h>

// DNRI step: B=32, N=100, D=4, H=256, K=4 (skip type 0), E=9900.
// R17: R11 skeleton (1 tile/block, 30KB LDS, grid 3200 — the proven local
// optimum) + the two correctness-proven R16 pieces: k2a writes m1G
// PRE-SWIZZLED, k2b stages via global_load_lds width=16 (async DMA, no VGPR
// round trip, no ds_write VALU). All 2-tile / dbuf / fusion variants reverted
// (R12-R16: each lost more co-residency than it gained overlap).

typedef __attribute__((ext_vector_type(4))) float f32x4;
typedef __attribute__((ext_vector_type(8))) short s16x8;
typedef __attribute__((ext_vector_type(4))) unsigned short u16x4;
typedef __attribute__((ext_vector_type(4))) unsigned int u32x4;
typedef __attribute__((ext_vector_type(2))) unsigned int u32x2;

#define DEV static __device__ __forceinline__

DEV unsigned short f2bf(float f) {
  unsigned int u = __builtin_bit_cast(unsigned int, f);
  u += 0x7fffu + ((u >> 16) & 1u);   // RNE
  return (unsigned short)(u >> 16);
}
DEV float bf2f(unsigned short h) {
  unsigned int u = ((unsigned int)h) << 16;
  return __builtin_bit_cast(float, u);
}
DEV float bflo(unsigned int u) { return __builtin_bit_cast(float, u << 16); }
DEV float bfhi(unsigned int u) { return __builtin_bit_cast(float, u & 0xffff0000u); }
DEV float exp2_fast(float x) { return __builtin_amdgcn_exp2f(x); }
DEV float tanh_fast(float x) {
  float e = exp2_fast(x * 2.885390082f);            // exp(2x)
  return 1.f - 2.f * __builtin_amdgcn_rcpf(e + 1.f);
}
DEV float sigmoid_fast(float x) {
  return __builtin_amdgcn_rcpf(1.f + exp2_fast(-1.442695041f * x));
}
DEV unsigned int pk_fp8x4(float a, float b, float c, float d) {
  int v = __builtin_amdgcn_cvt_pk_fp8_f32(a, b, 0, false);   // bytes 0,1
  v = __builtin_amdgcn_cvt_pk_fp8_f32(c, d, v, true);        // bytes 2,3
  return (unsigned int)v;
}
// async global->LDS DMA, 16B per lane; LDS dest = base + lane*16 (wave-uniform base)
DEV void gload_lds16(const unsigned char* g, unsigned char* l) {
  __builtin_amdgcn_global_load_lds(
      (const __attribute__((address_space(1))) void*)g,
      (__attribute__((address_space(3))) void*)l, 16, 0, 0);
}

// ---- LDS staging: 64 rows x 256 bf16, XOR-swizzled ----
DEV void stage_bf16_64(const unsigned short* __restrict__ src, unsigned char* smem, int tid) {
#pragma unroll
  for (int j = 0; j < 8; ++j) {
    int c = tid + 256 * j;
    int s = c >> 5, hc = c & 31;
    s16x8 v = *reinterpret_cast<const s16x8*>(src + s * 256 + hc * 8);
    int byte = (s * 512 + hc * 16) ^ ((s & 7) << 4);
    *reinterpret_cast<s16x8*>(smem + byte) = v;
  }
}
DEV void stage_f32_64(const float* __restrict__ src, unsigned char* smem, int tid) {
#pragma unroll
  for (int j = 0; j < 8; ++j) {
    int c = tid + 256 * j;
    int s = c >> 5, hc = c & 31;
    const float* p = src + s * 256 + hc * 8;
    f32x4 v0 = *reinterpret_cast<const f32x4*>(p);
    f32x4 v1 = *reinterpret_cast<const f32x4*>(p + 4);
    s16x8 o;
#pragma unroll
    for (int i = 0; i < 4; ++i) { o[i] = (short)f2bf(v0[i]); o[4 + i] = (short)f2bf(v1[i]); }
    int byte = (s * 512 + hc * 16) ^ ((s & 7) << 4);
    *reinterpret_cast<s16x8*>(smem + byte) = o;
  }
}
// staging that sums three f32 partial buffers -> bf16 swizzled LDS
DEV void stage_sum3_f32(const float* __restrict__ sa, const float* __restrict__ sb,
                        const float* __restrict__ sc, unsigned char* smem, int tid) {
#pragma unroll
  for (int j = 0; j < 8; ++j) {
    int c = tid + 256 * j;
    int s = c >> 5, hc = c & 31;
    int o4 = s * 256 + hc * 8;
    f32x4 a0 = *reinterpret_cast<const f32x4*>(sa + o4);
    f32x4 a1 = *reinterpret_cast<const f32x4*>(sa + o4 + 4);
    f32x4 b0 = *reinterpret_cast<const f32x4*>(sb + o4);
    f32x4 b1 = *reinterpret_cast<const f32x4*>(sb + o4 + 4);
    f32x4 c0 = *reinterpret_cast<const f32x4*>(sc + o4);
    f32x4 c1 = *reinterpret_cast<const f32x4*>(sc + o4 + 4);
    s16x8 o;
#pragma unroll
    for (int i = 0; i < 4; ++i) {
      o[i] = (short)f2bf(a0[i] + b0[i] + c0[i]);
      o[4 + i] = (short)f2bf(a1[i] + b1[i] + c1[i]);
    }
    int byte = (s * 512 + hc * 16) ^ ((s & 7) << 4);
    *reinterpret_cast<s16x8*>(smem + byte) = o;
  }
}

// ---- bf16 MFMA tile helper (A in swizzled LDS, B^T [n][k] bf16 in global) ----
template<int MF>
DEV void gemm_lds_tile(const unsigned char* smemA, const unsigned short* __restrict__ B,
                       int nb, int lane, f32x4 acc[][4]) {
  int li = lane & 15, lg = lane >> 4;
#pragma unroll
  for (int kk = 0; kk < 8; ++kk) {
    int kb = kk * 32 + lg * 8;
    s16x8 a[MF];
#pragma unroll
    for (int m = 0; m < MF; ++m) {
      int row = m * 16 + li;
      int byte = (row * 512 + kb * 2) ^ ((row & 7) << 4);
      a[m] = *reinterpret_cast<const s16x8*>(smemA + byte);
    }
#pragma unroll
    for (int n = 0; n < 4; ++n) {
      int col = nb + n * 16 + li;
      s16x8 bf = *reinterpret_cast<const s16x8*>(B + col * 256 + kb);
#pragma unroll
      for (int m = 0; m < MF; ++m)
        acc[m][n] = __builtin_amdgcn_mfma_f32_16x16x32_bf16(a[m], bf, acc[m][n], 0, 0, 0);
    }
  }
}

// ---- K0: bf16 transposes (W1a/W1b/Wh-family) ----
__global__ __launch_bounds__(256) void k0_pack(
    const float* __restrict__ msg_W1,
    const float* __restrict__ Whr, const float* __restrict__ Whi, const float* __restrict__ Whh,
    const float* __restrict__ Wo1, const float* __restrict__ Wo2,
    unsigned short* __restrict__ W1aT, unsigned short* __restrict__ W1bT,
    unsigned short* __restrict__ WhT) {
  int g = blockIdx.x * 256 + threadIdx.x;
  if (g < 196608) {               // W1aT[ti][n][k] = msg_W1[ti+1][k][n]
    int ti = g >> 16, rem = g & 65535, n = rem >> 8, k = rem & 255;
    W1aT[g] = f2bf(msg_W1[((ti + 1) * 512 + k) * 256 + n]);
  } else if (g < 393216) {        // W1bT[ti][n][k] = msg_W1[ti+1][256+k][n]
    int h = g - 196608; int ti = h >> 16, rem = h & 65535, n = rem >> 8, k = rem & 255;
    W1bT[h] = f2bf(msg_W1[((ti + 1) * 512 + 256 + k) * 256 + n]);
  } else if (g < 720896) {        // WhT: {Whr,Whi,Whh,Wo1,Wo2}^T
    int h = g - 393216; int mi = h >> 16, rem = h & 65535, n = rem >> 8, k = rem & 255;
    const float* s = mi == 0 ? Whr : mi == 1 ? Whi : mi == 2 ? Whh : mi == 3 ? Wo1 : Wo2;
    WhT[h] = f2bf(s[k * 256 + n]);
  }
}

// ---- K0q: W2 -> fp8 e4m3, layout [ti][col][k] (1B/elem) ----
__global__ __launch_bounds__(256) void k0_quant(
    const float* __restrict__ msg_W2, unsigned short* __restrict__ W2Q) {
  int g = blockIdx.x * 256 + threadIdx.x;          // 98304 = 3*256*128
  int ti = g >> 15, rem = g & 32767, col = rem >> 7, k2 = rem & 127;
  int k = k2 * 2;
  const float* src = msg_W2 + (size_t)(ti + 1) * 65536;
  float a = src[k * 256 + col], b = src[(k + 1) * 256 + col];
  int v = __builtin_amdgcn_cvt_pk_fp8_f32(a, b, 0, false);
  W2Q[g] = (unsigned short)(v & 0xffff);
}

// ---- Xpre[row][3*256] = inputs @ [Wir|Wii|Win] + biases ----
__global__ __launch_bounds__(256) void k_xpre(
    const float* __restrict__ inputs, const float* __restrict__ Wir, const float* __restrict__ bir,
    const float* __restrict__ Wii, const float* __restrict__ bii,
    const float* __restrict__ Win, const float* __restrict__ bin_, float* __restrict__ Xpre) {
  int g = blockIdx.x * 256 + threadIdx.x;   // 3200*768 exact
  int row = g / 768, c = g % 768, which = c >> 8, col = c & 255;
  const float* W = which == 0 ? Wir : which == 1 ? Wii : Win;
  const float* bb = which == 0 ? bir : which == 1 ? bii : bin_;
  const float* inp = inputs + row * 4;
  float s = bb[col];
#pragma unroll
  for (int d = 0; d < 4; ++d) s += inp[d] * W[d * 256 + col];
  Xpre[g] = s;
}

// ---- K1: Ha[ti] = hidden@W1a+b1 (bf16), Hb[ti] = hidden@W1b ----
__global__ __launch_bounds__(256) void k1_nodepre(
    const float* __restrict__ hidden, const float* __restrict__ msg_b1,
    const unsigned short* __restrict__ W1aT, const unsigned short* __restrict__ W1bT,
    unsigned short* __restrict__ Ha, unsigned short* __restrict__ Hb) {
  __shared__ alignas(16) unsigned char smem[32768];
  int tid = threadIdx.x, lane = tid & 63, wv = tid >> 6;
  int mt = blockIdx.x, g = blockIdx.y;
  stage_f32_64(hidden + (size_t)mt * 64 * 256, smem, tid);
  __syncthreads();
  int ti = g < 3 ? g : g - 3;
  const unsigned short* Bp = (g < 3 ? W1aT : W1bT) + ti * 65536;
  f32x4 zz = {0.f, 0.f, 0.f, 0.f};
  f32x4 acc[4][4];
#pragma unroll
  for (int m = 0; m < 4; ++m)
#pragma unroll
    for (int n = 0; n < 4; ++n) acc[m][n] = zz;
  gemm_lds_tile<4>(smem, Bp, wv * 64, lane, acc);
  unsigned short* dst = (g < 3 ? Ha : Hb) + (size_t)ti * 819200 + (size_t)mt * 64 * 256;
  int li = lane & 15, lg = lane >> 4;
#pragma unroll
  for (int n = 0; n < 4; ++n) {
    int col = wv * 64 + n * 16 + li;
    float bias = g < 3 ? msg_b1[(ti + 1) * 256 + col] : 0.f;
#pragma unroll
    for (int m = 0; m < 4; ++m)
#pragma unroll
      for (int q = 0; q < 4; ++q) {
        int row = m * 16 + lg * 4 + q;
        dst[row * 256 + col] = f2bf(acc[m][n][q] + bias);
      }
  }
}

// ---- K2a: streaming build of one type-slice of m1 (fp8, PRE-SWIZZLED) ----
// grid 3200 (b,r); no LDS, no barriers. m1G[bid] holds 28672B whose linear
// layout equals the swizzled-LDS image k2b reads (rule #21 both-sides).
__global__ __launch_bounds__(256) void k2a_build(
    const unsigned short* __restrict__ Ha, const unsigned short* __restrict__ Hb,
    unsigned char* __restrict__ m1G, int ti) {
  int tid = threadIdx.x;
  int bid0 = blockIdx.x;
  int bid = (bid0 & 7) * 400 + (bid0 >> 3);   // XCD-contiguous (3200 = 8*400)
  int b = bid / 100, r = bid % 100;
  int hc = tid & 31, srow0 = tid >> 5;

  u32x4 hau = *reinterpret_cast<const u32x4*>(
      Ha + ((size_t)ti * 3200 + b * 100 + r) * 256 + hc * 8);
  float ha_f[8];
#pragma unroll
  for (int i = 0; i < 4; ++i) { ha_f[2 * i] = bflo(hau[i]); ha_f[2 * i + 1] = bfhi(hau[i]); }
  const unsigned short* HbB = Hb + ((size_t)ti * 3200 + b * 100) * 256;
  unsigned char* dst = m1G + (size_t)bid * 28672;
#pragma unroll
  for (int j = 0; j < 14; ++j) {
    int s = srow0 + 8 * j;
    u32x2 o = {0u, 0u};
    if (s < 99) {
      int snode = s + (s >= r ? 1 : 0);
      u32x4 hb = *reinterpret_cast<const u32x4*>(HbB + snode * 256 + hc * 8);
      float t[8];
#pragma unroll
      for (int i = 0; i < 4; ++i) {
        t[2 * i] = tanh_fast(ha_f[2 * i] + bflo(hb[i]));
        t[2 * i + 1] = tanh_fast(ha_f[2 * i + 1] + bfhi(hb[i]));
      }
      o[0] = pk_fp8x4(t[0], t[1], t[2], t[3]);
      o[1] = pk_fp8x4(t[4], t[5], t[6], t[7]);
    }
    int byte = (s * 256 + hc * 8) ^ ((s & 7) << 4);   // pre-swizzle on global write
    *reinterpret_cast<u32x2*>(dst + byte) = o;
  }
}

// ---- K2b: DMA-stage m1 slice -> LDS (linear dest), fp8 GEMM, tanh epilogue ----
// grid 3200, 1 tile/block (R11 skeleton).
// LDS: m1 fp8 image @0 (28672) | w [112] f32 @28672 | agg [256] f32 @29120
__global__ __launch_bounds__(256) void k2b_gemm(
    const float* __restrict__ edges, const float* __restrict__ msg_b2,
    const unsigned char* __restrict__ m1G, const unsigned char* __restrict__ W2Q,
    float* __restrict__ pagg, int ti) {
  __shared__ alignas(16) unsigned char smem[30144];
  float* w_s = (float*)(smem + 28672);
  float* agg_s = (float*)(smem + 29120);
  int tid = threadIdx.x, lane = tid & 63, wv = tid >> 6;
  int li = lane & 15, lg = lane >> 4;
  int bid0 = blockIdx.x;
  int bid = (bid0 & 7) * 400 + (bid0 >> 3);
  int b = bid / 100, r = bid % 100;

  // stage tile via async DMA (linear LDS dest; source pre-swizzled by k2a):
  // 28 chunks of 1024B; wave wv handles chunks [wv*7, wv*7+7)
  const unsigned char* src = m1G + (size_t)bid * 28672;
#pragma unroll
  for (int j = 0; j < 7; ++j) {
    int chunk = wv * 7 + j;
    gload_lds16(src + chunk * 1024 + lane * 16, smem + chunk * 1024);
  }
  // edge weights for this type (analytic dense edge index) — overlaps DMA
  {
    float w0 = 0.f;
    if (tid < 99) {
      int snode = tid + (tid >= r ? 1 : 0);
      int e = snode * 99 + r - (r > snode ? 1 : 0);
      w0 = edges[(size_t)(b * 9900 + e) * 4 + (ti + 1)] * (1.f / 297.f);
    }
    if (tid < 112) w_s[tid] = w0;
  }
  __syncthreads();   // drains DMA (vmcnt) + w_s visible

  float b2r[4];
#pragma unroll
  for (int n = 0; n < 4; ++n)
    b2r[n] = msg_b2[(ti + 1) * 256 + wv * 64 + n * 16 + li];

  float aggacc[4] = {0.f, 0.f, 0.f, 0.f};
  f32x4 zz = {0.f, 0.f, 0.f, 0.f};
  const unsigned char* Bq = W2Q + (size_t)ti * 65536;
#pragma unroll
  for (int p = 0; p < 2; ++p) {
    f32x4 acc[7][2];
#pragma unroll
    for (int m = 0; m < 7; ++m) { acc[m][0] = zz; acc[m][1] = zz; }
#pragma unroll
    for (int kk = 0; kk < 8; ++kk) {
      int ko = kk * 32 + lg * 8;
      long a[7];
#pragma unroll
      for (int m = 0; m < 7; ++m) {
        int row = m * 16 + li;
        int byte = (row * 256 + ko) ^ ((row & 7) << 4);
        a[m] = *reinterpret_cast<const long*>(smem + byte);
      }
#pragma unroll
      for (int n = 0; n < 2; ++n) {
        int col = wv * 64 + p * 32 + n * 16 + li;
        long bq = *reinterpret_cast<const long*>(Bq + col * 256 + ko);
#pragma unroll
        for (int m = 0; m < 7; ++m)
          acc[m][n] = __builtin_amdgcn_mfma_f32_16x16x32_fp8_fp8(a[m], bq, acc[m][n], 0, 0, 0);
      }
    }
    // epilogue for this pass (reg + broadcast-LDS only)
#pragma unroll
    for (int n = 0; n < 2; ++n) {
      float b2v = b2r[p * 2 + n];
      float pa = 0.f;
#pragma unroll
      for (int m = 0; m < 7; ++m) {
        f32x4 wf = *reinterpret_cast<const f32x4*>(w_s + m * 16 + lg * 4);
#pragma unroll
        for (int q = 0; q < 4; ++q)
          pa += tanh_fast(acc[m][n][q] + b2v) * wf[q];
      }
      aggacc[p * 2 + n] += pa;
    }
  }

  // reduce row-groups (C layout: col=lane&15, row=(lane>>4)*4+q)
#pragma unroll
  for (int n = 0; n < 4; ++n) {
    float v = aggacc[n];
    v += __shfl_xor(v, 16);
    v += __shfl_xor(v, 32);
    if (lane < 16) agg_s[wv * 64 + n * 16 + lane] = v;
  }
  __syncthreads();
  pagg[(size_t)ti * 819200 + (size_t)bid * 256 + tid] = agg_s[tid];
}

// ---- K3: RIH[y] = (pagg0+pagg1+pagg2) @ {Whr,Whi,Whh}[y] (f32 out) ----
__global__ __launch_bounds__(256) void k3_gemm(
    const float* __restrict__ pagg, const unsigned short* __restrict__ WhT,
    float* __restrict__ RIH) {
  __shared__ alignas(16) unsigned char smem[32768];
  int tid = threadIdx.x, lane = tid & 63, wv = tid >> 6;
  int mt = blockIdx.x, y = blockIdx.y;
  size_t base = (size_t)mt * 64 * 256;
  stage_sum3_f32(pagg + base, pagg + 819200 + base, pagg + 1638400 + base, smem, tid);
  __syncthreads();
  f32x4 zz = {0.f, 0.f, 0.f, 0.f};
  f32x4 acc[4][4];
#pragma unroll
  for (int m = 0; m < 4; ++m)
#pragma unroll
    for (int n = 0; n < 4; ++n) acc[m][n] = zz;
  gemm_lds_tile<4>(smem, WhT + y * 65536, wv * 64, lane, acc);
  float* dst = RIH + (size_t)y * 819200 + base;
  int li = lane & 15, lg = lane >> 4;
#pragma unroll
  for (int n = 0; n < 4; ++n) {
    int col = wv * 64 + n * 16 + li;
#pragma unroll
    for (int m = 0; m < 4; ++m)
#pragma unroll
      for (int q = 0; q < 4; ++q)
        dst[(m * 16 + lg * 4 + q) * 256 + col] = acc[m][n][q];
  }
}

// ---- K4: elementwise GRU combine -> hidden_new ----
__global__ __launch_bounds__(256) void k4_gru(
    const float* __restrict__ Xpre, const float* __restrict__ RIH,
    const float* __restrict__ hidden, float* __restrict__ out, unsigned short* __restrict__ hnewbf) {
  int idx = blockIdx.x * 256 + threadIdx.x;
  int row = idx >> 8, col = idx & 255;
  float xr = Xpre[row * 768 + col];
  float xi = Xpre[row * 768 + 256 + col];
  float xn = Xpre[row * 768 + 512 + col];
  float rr = sigmoid_fast(xr + RIH[idx]);
  float ig = sigmoid_fast(xi + RIH[819200 + idx]);
  float nn = tanh_fast(xn + rr * RIH[1638400 + idx]);
  float hn = (1.f - ig) * nn + ig * hidden[idx];
  out[12800 + idx] = hn;
  hnewbf[idx] = f2bf(hn);
}

// ---- K5/K6: dst = relu(A @ WT + bias) (bf16) ----
__global__ __launch_bounds__(256) void k_mlp(
    const unsigned short* __restrict__ A, const unsigned short* __restrict__ WT,
    const float* __restrict__ bias, unsigned short* __restrict__ dst) {
  __shared__ alignas(16) unsigned char smem[32768];
  int tid = threadIdx.x, lane = tid & 63, wv = tid >> 6;
  int mt = blockIdx.x;
  stage_bf16_64(A + (size_t)mt * 64 * 256, smem, tid);
  __syncthreads();
  f32x4 zz = {0.f, 0.f, 0.f, 0.f};
  f32x4 acc[4][4];
#pragma unroll
  for (int m = 0; m < 4; ++m)
#pragma unroll
    for (int n = 0; n < 4; ++n) acc[m][n] = zz;
  gemm_lds_tile<4>(smem, WT, wv * 64, lane, acc);
  unsigned short* d = dst + (size_t)mt * 64 * 256;
  int li = lane & 15, lg = lane >> 4;
#pragma unroll
  for (int n = 0; n < 4; ++n) {
    int col = wv * 64 + n * 16 + li;
    float bv = bias[col];
#pragma unroll
    for (int m = 0; m < 4; ++m)
#pragma unroll
      for (int q = 0; q < 4; ++q) {
        float v = fmaxf(acc[m][n][q] + bv, 0.f);
        d[(m * 16 + lg * 4 + q) * 256 + col] = f2bf(v);
      }
  }
}

// ---- K7: pred = inputs + pred2 @ Wo3 + bo3 ----
__global__ __launch_bounds__(64) void k7_out(
    const unsigned short* __restrict__ pred2, const float* __restrict__ Wo3,
    const float* __restrict__ bo3, const float* __restrict__ inputs, float* __restrict__ out) {
  int row = blockIdx.x, lane = threadIdx.x;
  u16x4 p = *reinterpret_cast<const u16x4*>(pred2 + (size_t)row * 256 + lane * 4);
  float s0 = 0.f, s1 = 0.f, s2 = 0.f, s3 = 0.f;
#pragma unroll
  for (int j = 0; j < 4; ++j) {
    float pv = bf2f(p[j]);
    const float* wr = Wo3 + (lane * 4 + j) * 4;
    s0 += pv * wr[0]; s1 += pv * wr[1]; s2 += pv * wr[2]; s3 += pv * wr[3];
  }
#pragma unroll
  for (int off = 32; off >= 1; off >>= 1) {
    s0 += __shfl_xor(s0, off); s1 += __shfl_xor(s1, off);
    s2 += __shfl_xor(s2, off); s3 += __shfl_xor(s3, off);
  }
  if (lane == 0) {
    out[row * 4 + 0] = inputs[row * 4 + 0] + s0 + bo3[0];
    out[row * 4 + 1] = inputs[row * 4 + 1] + s1 + bo3[1];
    out[row * 4 + 2] = inputs[row * 4 + 2] + s2 + bo3[2];
    out[row * 4 + 3] = inputs[row * 4 + 3] + s3 + bo3[3];
  }
}

extern "C" void kernel_launch(void* const* d_in, const int* in_sizes, int n_in,
                              void* d_out, int out_size, void* d_ws, size_t ws_size,
                              hipStream_t stream) {
  const float* inputs = (const float*)d_in[0];
  const float* hidden = (const float*)d_in[1];
  const float* edges  = (const float*)d_in[2];
  const float* msg_W1 = (const float*)d_in[3];
  const float* msg_b1 = (const float*)d_in[4];
  const float* msg_W2 = (const float*)d_in[5];
  const float* msg_b2 = (const float*)d_in[6];
  const float* Whr = (const float*)d_in[7];
  const float* Whi = (const float*)d_in[8];
  const float* Whh = (const float*)d_in[9];
  const float* Wir = (const float*)d_in[10];
  const float* bir = (const float*)d_in[11];
  const float* Wii = (const float*)d_in[12];
  const float* bii = (const float*)d_in[13];
  const float* Win = (const float*)d_in[14];
  const float* bin_ = (const float*)d_in[15];
  const float* Wo1 = (const float*)d_in[16];
  const float* bo1 = (const float*)d_in[17];
  const float* Wo2 = (const float*)d_in[18];
  const float* bo2 = (const float*)d_in[19];
  const float* Wo3 = (const float*)d_in[20];
  const float* bo3 = (const float*)d_in[21];
  float* out = (float*)d_out;

  char* ws = (char*)d_ws;
  size_t off = 0;
  auto take = [&](size_t bytes) -> char* {
    char* p = ws + off;
    off += (bytes + 511) & ~(size_t)511;
    return p;
  };
  unsigned short* W1aT = (unsigned short*)take(196608 * 2);
  unsigned short* W1bT = (unsigned short*)take(196608 * 2);
  unsigned short* W2Q  = (unsigned short*)take(196608);      // fp8 [3][256][256]
  unsigned short* WhT  = (unsigned short*)take(327680 * 2);  // WhrT|WhiT|WhhT|Wo1T|Wo2T
  unsigned short* Ha   = (unsigned short*)take(2457600 * 2); // [3][3200][256]
  unsigned short* Hb   = (unsigned short*)take(2457600 * 2);
  float* pagg = (float*)take(3 * 819200 * 4);                // [3][3200][256] partial agg
  unsigned char* m1G = (unsigned char*)take((size_t)3200 * 28672); // one ti slice, 91.75MB
  float* Xpre = (float*)take(2457600 * 4);                   // [3200][768]
  float* RIH  = (float*)take(2457600 * 4);                   // [3][3200][256]
  unsigned short* hnewbf = (unsigned short*)take(819200 * 2);
  unsigned short* pred1  = (unsigned short*)take(819200 * 2);
  unsigned short* pred2  = (unsigned short*)take(819200 * 2);

  k0_pack<<<2816, 256, 0, stream>>>(msg_W1, Whr, Whi, Whh, Wo1, Wo2, W1aT, W1bT, WhT);
  k0_quant<<<384, 256, 0, stream>>>(msg_W2, W2Q);
  k_xpre<<<9600, 256, 0, stream>>>(inputs, Wir, bir, Wii, bii, Win, bin_, Xpre);
  k1_nodepre<<<dim3(50, 6), 256, 0, stream>>>(hidden, msg_b1, W1aT, W1bT, Ha, Hb);
  for (int ti = 0; ti < 3; ++ti) {
    k2a_build<<<3200, 256, 0, stream>>>(Ha, Hb, m1G, ti);
    k2b_gemm<<<3200, 256, 0, stream>>>(edges, msg_b2, m1G,
                                       (const unsigned char*)W2Q, pagg, ti);
  }
  k3_gemm<<<dim3(50, 3), 256, 0, stream>>>(pagg, WhT, RIH);
  k4_gru<<<3200, 256, 0, stream>>>(Xpre, RIH, hidden, out, hnewbf);
  k_mlp<<<50, 256, 0, stream>>>(hnewbf, WhT + 196608, bo1, pred1);
  k_mlp<<<50, 256, 0, stream>>>(pred1, WhT + 262144, bo2, pred2);
  k7_out<<<3200, 64, 0, stream>>>(pred2, Wo3, bo3, inputs, out);
}

// Round 19
// 333.897 us; speedup vs baseline: 1.3965x; 1.0671x over previous
//
#include <hip/hip_runtime.h>
#include <hip/hip_bf16.h>

// DNRI step: B=32, N=100, D=4, H=256, K=4 (skip type 0), E=9900.
// R18: k2 chain frozen at R17 (six variants failed to beat ~73us k2b).
// Harvest the non-k2 tail: k_mlp grid 50->(50,4), k3 (50,3)->(50,3,2),
// k1 (50,6)->(50,6,2); k0_pack+k0_quant+k_xpre merged into one launch.

typedef __attribute__((ext_vector_type(4))) float f32x4;
typedef __attribute__((ext_vector_type(8))) short s16x8;
typedef __attribute__((ext_vector_type(4))) unsigned short u16x4;
typedef __attribute__((ext_vector_type(4))) unsigned int u32x4;
typedef __attribute__((ext_vector_type(2))) unsigned int u32x2;

#define DEV static __device__ __forceinline__

DEV unsigned short f2bf(float f) {
  unsigned int u = __builtin_bit_cast(unsigned int, f);
  u += 0x7fffu + ((u >> 16) & 1u);   // RNE
  return (unsigned short)(u >> 16);
}
DEV float bf2f(unsigned short h) {
  unsigned int u = ((unsigned int)h) << 16;
  return __builtin_bit_cast(float, u);
}
DEV float bflo(unsigned int u) { return __builtin_bit_cast(float, u << 16); }
DEV float bfhi(unsigned int u) { return __builtin_bit_cast(float, u & 0xffff0000u); }
DEV float exp2_fast(float x) { return __builtin_amdgcn_exp2f(x); }
DEV float tanh_fast(float x) {
  float e = exp2_fast(x * 2.885390082f);            // exp(2x)
  return 1.f - 2.f * __builtin_amdgcn_rcpf(e + 1.f);
}
DEV float sigmoid_fast(float x) {
  return __builtin_amdgcn_rcpf(1.f + exp2_fast(-1.442695041f * x));
}
DEV unsigned int pk_fp8x4(float a, float b, float c, float d) {
  int v = __builtin_amdgcn_cvt_pk_fp8_f32(a, b, 0, false);   // bytes 0,1
  v = __builtin_amdgcn_cvt_pk_fp8_f32(c, d, v, true);        // bytes 2,3
  return (unsigned int)v;
}
// async global->LDS DMA, 16B per lane; LDS dest = base + lane*16 (wave-uniform base)
DEV void gload_lds16(const unsigned char* g, unsigned char* l) {
  __builtin_amdgcn_global_load_lds(
      (const __attribute__((address_space(1))) void*)g,
      (__attribute__((address_space(3))) void*)l, 16, 0, 0);
}

// ---- LDS staging: 64 rows x 256 bf16, XOR-swizzled ----
DEV void stage_bf16_64(const unsigned short* __restrict__ src, unsigned char* smem, int tid) {
#pragma unroll
  for (int j = 0; j < 8; ++j) {
    int c = tid + 256 * j;
    int s = c >> 5, hc = c & 31;
    s16x8 v = *reinterpret_cast<const s16x8*>(src + s * 256 + hc * 8);
    int byte = (s * 512 + hc * 16) ^ ((s & 7) << 4);
    *reinterpret_cast<s16x8*>(smem + byte) = v;
  }
}
DEV void stage_f32_64(const float* __restrict__ src, unsigned char* smem, int tid) {
#pragma unroll
  for (int j = 0; j < 8; ++j) {
    int c = tid + 256 * j;
    int s = c >> 5, hc = c & 31;
    const float* p = src + s * 256 + hc * 8;
    f32x4 v0 = *reinterpret_cast<const f32x4*>(p);
    f32x4 v1 = *reinterpret_cast<const f32x4*>(p + 4);
    s16x8 o;
#pragma unroll
    for (int i = 0; i < 4; ++i) { o[i] = (short)f2bf(v0[i]); o[4 + i] = (short)f2bf(v1[i]); }
    int byte = (s * 512 + hc * 16) ^ ((s & 7) << 4);
    *reinterpret_cast<s16x8*>(smem + byte) = o;
  }
}
// staging that sums three f32 partial buffers -> bf16 swizzled LDS
DEV void stage_sum3_f32(const float* __restrict__ sa, const float* __restrict__ sb,
                        const float* __restrict__ sc, unsigned char* smem, int tid) {
#pragma unroll
  for (int j = 0; j < 8; ++j) {
    int c = tid + 256 * j;
    int s = c >> 5, hc = c & 31;
    int o4 = s * 256 + hc * 8;
    f32x4 a0 = *reinterpret_cast<const f32x4*>(sa + o4);
    f32x4 a1 = *reinterpret_cast<const f32x4*>(sa + o4 + 4);
    f32x4 b0 = *reinterpret_cast<const f32x4*>(sb + o4);
    f32x4 b1 = *reinterpret_cast<const f32x4*>(sb + o4 + 4);
    f32x4 c0 = *reinterpret_cast<const f32x4*>(sc + o4);
    f32x4 c1 = *reinterpret_cast<const f32x4*>(sc + o4 + 4);
    s16x8 o;
#pragma unroll
    for (int i = 0; i < 4; ++i) {
      o[i] = (short)f2bf(a0[i] + b0[i] + c0[i]);
      o[4 + i] = (short)f2bf(a1[i] + b1[i] + c1[i]);
    }
    int byte = (s * 512 + hc * 16) ^ ((s & 7) << 4);
    *reinterpret_cast<s16x8*>(smem + byte) = o;
  }
}

// ---- bf16 MFMA tile helper: A (MF*16 x 256) in swizzled LDS, B^T [n][k] bf16
// in global; wave computes NF 16-col fragments starting at col nb. ----
template<int MF, int NF>
DEV void gemm_tile(const unsigned char* smemA, const unsigned short* __restrict__ B,
                   int nb, int lane, f32x4 acc[MF][NF]) {
  int li = lane & 15, lg = lane >> 4;
#pragma unroll
  for (int kk = 0; kk < 8; ++kk) {
    int kb = kk * 32 + lg * 8;
    s16x8 a[MF];
#pragma unroll
    for (int m = 0; m < MF; ++m) {
      int row = m * 16 + li;
      int byte = (row * 512 + kb * 2) ^ ((row & 7) << 4);
      a[m] = *reinterpret_cast<const s16x8*>(smemA + byte);
    }
#pragma unroll
    for (int n = 0; n < NF; ++n) {
      int col = nb + n * 16 + li;
      s16x8 bf = *reinterpret_cast<const s16x8*>(B + col * 256 + kb);
#pragma unroll
      for (int m = 0; m < MF; ++m)
        acc[m][n] = __builtin_amdgcn_mfma_f32_16x16x32_bf16(a[m], bf, acc[m][n], 0, 0, 0);
    }
  }
}

// ---- KPRE: merged k0_pack + k0_quant + k_xpre (3 launches -> 1) ----
__global__ __launch_bounds__(256) void kpre(
    const float* __restrict__ msg_W1, const float* __restrict__ msg_W2,
    const float* __restrict__ Whr, const float* __restrict__ Whi, const float* __restrict__ Whh,
    const float* __restrict__ Wo1, const float* __restrict__ Wo2,
    const float* __restrict__ inputs, const float* __restrict__ Wir, const float* __restrict__ bir,
    const float* __restrict__ Wii, const float* __restrict__ bii,
    const float* __restrict__ Win, const float* __restrict__ bin_,
    unsigned short* __restrict__ W1aT, unsigned short* __restrict__ W1bT,
    unsigned short* __restrict__ WhT, unsigned short* __restrict__ W2Q,
    float* __restrict__ Xpre) {
  int blk = blockIdx.x, tid = threadIdx.x;
  if (blk < 2816) {                    // --- pack ---
    int g = blk * 256 + tid;
    if (g < 196608) {                  // W1aT[ti][n][k] = msg_W1[ti+1][k][n]
      int ti = g >> 16, rem = g & 65535, n = rem >> 8, k = rem & 255;
      W1aT[g] = f2bf(msg_W1[((ti + 1) * 512 + k) * 256 + n]);
    } else if (g < 393216) {           // W1bT[ti][n][k] = msg_W1[ti+1][256+k][n]
      int h = g - 196608; int ti = h >> 16, rem = h & 65535, n = rem >> 8, k = rem & 255;
      W1bT[h] = f2bf(msg_W1[((ti + 1) * 512 + 256 + k) * 256 + n]);
    } else if (g < 720896) {           // WhT: {Whr,Whi,Whh,Wo1,Wo2}^T
      int h = g - 393216; int mi = h >> 16, rem = h & 65535, n = rem >> 8, k = rem & 255;
      const float* s = mi == 0 ? Whr : mi == 1 ? Whi : mi == 2 ? Whh : mi == 3 ? Wo1 : Wo2;
      WhT[h] = f2bf(s[k * 256 + n]);
    }
  } else if (blk < 3200) {             // --- quant W2 -> fp8 [ti][col][k] ---
    int g = (blk - 2816) * 256 + tid;  // 98304 = 3*256*128
    int ti = g >> 15, rem = g & 32767, col = rem >> 7, k2 = rem & 127;
    int k = k2 * 2;
    const float* src = msg_W2 + (size_t)(ti + 1) * 65536;
    float a = src[k * 256 + col], b = src[(k + 1) * 256 + col];
    int v = __builtin_amdgcn_cvt_pk_fp8_f32(a, b, 0, false);
    W2Q[g] = (unsigned short)(v & 0xffff);
  } else {                             // --- xpre ---
    int g = (blk - 3200) * 256 + tid;  // 3200*768 exact
    int row = g / 768, c = g % 768, which = c >> 8, col = c & 255;
    const float* W = which == 0 ? Wir : which == 1 ? Wii : Win;
    const float* bb = which == 0 ? bir : which == 1 ? bii : bin_;
    const float* inp = inputs + row * 4;
    float s = bb[col];
#pragma unroll
    for (int d = 0; d < 4; ++d) s += inp[d] * W[d * 256 + col];
    Xpre[g] = s;
  }
}

// ---- K1: Ha[ti] = hidden@W1a+b1 (bf16), Hb[ti] = hidden@W1b; cols split by z ----
__global__ __launch_bounds__(256) void k1_nodepre(
    const float* __restrict__ hidden, const float* __restrict__ msg_b1,
    const unsigned short* __restrict__ W1aT, const unsigned short* __restrict__ W1bT,
    unsigned short* __restrict__ Ha, unsigned short* __restrict__ Hb) {
  __shared__ alignas(16) unsigned char smem[32768];
  int tid = threadIdx.x, lane = tid & 63, wv = tid >> 6;
  int mt = blockIdx.x, g = blockIdx.y, z = blockIdx.z;
  stage_f32_64(hidden + (size_t)mt * 64 * 256, smem, tid);
  __syncthreads();
  int ti = g < 3 ? g : g - 3;
  const unsigned short* Bp = (g < 3 ? W1aT : W1bT) + ti * 65536;
  int nb = z * 128 + wv * 32;
  f32x4 zz = {0.f, 0.f, 0.f, 0.f};
  f32x4 acc[4][2];
#pragma unroll
  for (int m = 0; m < 4; ++m) { acc[m][0] = zz; acc[m][1] = zz; }
  gemm_tile<4, 2>(smem, Bp, nb, lane, acc);
  unsigned short* dst = (g < 3 ? Ha : Hb) + (size_t)ti * 819200 + (size_t)mt * 64 * 256;
  int li = lane & 15, lg = lane >> 4;
#pragma unroll
  for (int n = 0; n < 2; ++n) {
    int col = nb + n * 16 + li;
    float bias = g < 3 ? msg_b1[(ti + 1) * 256 + col] : 0.f;
#pragma unroll
    for (int m = 0; m < 4; ++m)
#pragma unroll
      for (int q = 0; q < 4; ++q) {
        int row = m * 16 + lg * 4 + q;
        dst[row * 256 + col] = f2bf(acc[m][n][q] + bias);
      }
  }
}

// ---- K2a: streaming build of one type-slice of m1 (fp8, PRE-SWIZZLED) ----
__global__ __launch_bounds__(256) void k2a_build(
    const unsigned short* __restrict__ Ha, const unsigned short* __restrict__ Hb,
    unsigned char* __restrict__ m1G, int ti) {
  int tid = threadIdx.x;
  int bid0 = blockIdx.x;
  int bid = (bid0 & 7) * 400 + (bid0 >> 3);   // XCD-contiguous (3200 = 8*400)
  int b = bid / 100, r = bid % 100;
  int hc = tid & 31, srow0 = tid >> 5;

  u32x4 hau = *reinterpret_cast<const u32x4*>(
      Ha + ((size_t)ti * 3200 + b * 100 + r) * 256 + hc * 8);
  float ha_f[8];
#pragma unroll
  for (int i = 0; i < 4; ++i) { ha_f[2 * i] = bflo(hau[i]); ha_f[2 * i + 1] = bfhi(hau[i]); }
  const unsigned short* HbB = Hb + ((size_t)ti * 3200 + b * 100) * 256;
  unsigned char* dst = m1G + (size_t)bid * 28672;
#pragma unroll
  for (int j = 0; j < 14; ++j) {
    int s = srow0 + 8 * j;
    u32x2 o = {0u, 0u};
    if (s < 99) {
      int snode = s + (s >= r ? 1 : 0);
      u32x4 hb = *reinterpret_cast<const u32x4*>(HbB + snode * 256 + hc * 8);
      float t[8];
#pragma unroll
      for (int i = 0; i < 4; ++i) {
        t[2 * i] = tanh_fast(ha_f[2 * i] + bflo(hb[i]));
        t[2 * i + 1] = tanh_fast(ha_f[2 * i + 1] + bfhi(hb[i]));
      }
      o[0] = pk_fp8x4(t[0], t[1], t[2], t[3]);
      o[1] = pk_fp8x4(t[4], t[5], t[6], t[7]);
    }
    int byte = (s * 256 + hc * 8) ^ ((s & 7) << 4);   // pre-swizzle on global write
    *reinterpret_cast<u32x2*>(dst + byte) = o;
  }
}

// ---- K2b: DMA-stage m1 slice -> LDS (linear dest), fp8 GEMM, tanh epilogue ----
// grid 3200, 1 tile/block.
// LDS: m1 fp8 image @0 (28672) | w [112] f32 @28672 | agg [256] f32 @29120
__global__ __launch_bounds__(256) void k2b_gemm(
    const float* __restrict__ edges, const float* __restrict__ msg_b2,
    const unsigned char* __restrict__ m1G, const unsigned char* __restrict__ W2Q,
    float* __restrict__ pagg, int ti) {
  __shared__ alignas(16) unsigned char smem[30144];
  float* w_s = (float*)(smem + 28672);
  float* agg_s = (float*)(smem + 29120);
  int tid = threadIdx.x, lane = tid & 63, wv = tid >> 6;
  int li = lane & 15, lg = lane >> 4;
  int bid0 = blockIdx.x;
  int bid = (bid0 & 7) * 400 + (bid0 >> 3);
  int b = bid / 100, r = bid % 100;

  // stage tile via async DMA (linear LDS dest; source pre-swizzled by k2a)
  const unsigned char* src = m1G + (size_t)bid * 28672;
#pragma unroll
  for (int j = 0; j < 7; ++j) {
    int chunk = wv * 7 + j;
    gload_lds16(src + chunk * 1024 + lane * 16, smem + chunk * 1024);
  }
  // edge weights for this type (analytic dense edge index) — overlaps DMA
  {
    float w0 = 0.f;
    if (tid < 99) {
      int snode = tid + (tid >= r ? 1 : 0);
      int e = snode * 99 + r - (r > snode ? 1 : 0);
      w0 = edges[(size_t)(b * 9900 + e) * 4 + (ti + 1)] * (1.f / 297.f);
    }
    if (tid < 112) w_s[tid] = w0;
  }
  __syncthreads();   // drains DMA (vmcnt) + w_s visible

  float b2r[4];
#pragma unroll
  for (int n = 0; n < 4; ++n)
    b2r[n] = msg_b2[(ti + 1) * 256 + wv * 64 + n * 16 + li];

  float aggacc[4] = {0.f, 0.f, 0.f, 0.f};
  f32x4 zz = {0.f, 0.f, 0.f, 0.f};
  const unsigned char* Bq = W2Q + (size_t)ti * 65536;
#pragma unroll
  for (int p = 0; p < 2; ++p) {
    f32x4 acc[7][2];
#pragma unroll
    for (int m = 0; m < 7; ++m) { acc[m][0] = zz; acc[m][1] = zz; }
#pragma unroll
    for (int kk = 0; kk < 8; ++kk) {
      int ko = kk * 32 + lg * 8;
      long a[7];
#pragma unroll
      for (int m = 0; m < 7; ++m) {
        int row = m * 16 + li;
        int byte = (row * 256 + ko) ^ ((row & 7) << 4);
        a[m] = *reinterpret_cast<const long*>(smem + byte);
      }
#pragma unroll
      for (int n = 0; n < 2; ++n) {
        int col = wv * 64 + p * 32 + n * 16 + li;
        long bq = *reinterpret_cast<const long*>(Bq + col * 256 + ko);
#pragma unroll
        for (int m = 0; m < 7; ++m)
          acc[m][n] = __builtin_amdgcn_mfma_f32_16x16x32_fp8_fp8(a[m], bq, acc[m][n], 0, 0, 0);
      }
    }
    // epilogue for this pass (reg + broadcast-LDS only)
#pragma unroll
    for (int n = 0; n < 2; ++n) {
      float b2v = b2r[p * 2 + n];
      float pa = 0.f;
#pragma unroll
      for (int m = 0; m < 7; ++m) {
        f32x4 wf = *reinterpret_cast<const f32x4*>(w_s + m * 16 + lg * 4);
#pragma unroll
        for (int q = 0; q < 4; ++q)
          pa += tanh_fast(acc[m][n][q] + b2v) * wf[q];
      }
      aggacc[p * 2 + n] += pa;
    }
  }

  // reduce row-groups (C layout: col=lane&15, row=(lane>>4)*4+q)
#pragma unroll
  for (int n = 0; n < 4; ++n) {
    float v = aggacc[n];
    v += __shfl_xor(v, 16);
    v += __shfl_xor(v, 32);
    if (lane < 16) agg_s[wv * 64 + n * 16 + lane] = v;
  }
  __syncthreads();
  pagg[(size_t)ti * 819200 + (size_t)bid * 256 + tid] = agg_s[tid];
}

// ---- K3: RIH[y] = (pagg0+pagg1+pagg2) @ {Whr,Whi,Whh}[y]; cols split by z ----
__global__ __launch_bounds__(256) void k3_gemm(
    const float* __restrict__ pagg, const unsigned short* __restrict__ WhT,
    float* __restrict__ RIH) {
  __shared__ alignas(16) unsigned char smem[32768];
  int tid = threadIdx.x, lane = tid & 63, wv = tid >> 6;
  int mt = blockIdx.x, y = blockIdx.y, z = blockIdx.z;
  size_t base = (size_t)mt * 64 * 256;
  stage_sum3_f32(pagg + base, pagg + 819200 + base, pagg + 1638400 + base, smem, tid);
  __syncthreads();
  int nb = z * 128 + wv * 32;
  f32x4 zz = {0.f, 0.f, 0.f, 0.f};
  f32x4 acc[4][2];
#pragma unroll
  for (int m = 0; m < 4; ++m) { acc[m][0] = zz; acc[m][1] = zz; }
  gemm_tile<4, 2>(smem, WhT + y * 65536, nb, lane, acc);
  float* dst = RIH + (size_t)y * 819200 + base;
  int li = lane & 15, lg = lane >> 4;
#pragma unroll
  for (int n = 0; n < 2; ++n) {
    int col = nb + n * 16 + li;
#pragma unroll
    for (int m = 0; m < 4; ++m)
#pragma unroll
      for (int q = 0; q < 4; ++q)
        dst[(m * 16 + lg * 4 + q) * 256 + col] = acc[m][n][q];
  }
}

// ---- K4: elementwise GRU combine -> hidden_new ----
__global__ __launch_bounds__(256) void k4_gru(
    const float* __restrict__ Xpre, const float* __restrict__ RIH,
    const float* __restrict__ hidden, float* __restrict__ out, unsigned short* __restrict__ hnewbf) {
  int idx = blockIdx.x * 256 + threadIdx.x;
  int row = idx >> 8, col = idx & 255;
  float xr = Xpre[row * 768 + col];
  float xi = Xpre[row * 768 + 256 + col];
  float xn = Xpre[row * 768 + 512 + col];
  float rr = sigmoid_fast(xr + RIH[idx]);
  float ig = sigmoid_fast(xi + RIH[819200 + idx]);
  float nn = tanh_fast(xn + rr * RIH[1638400 + idx]);
  float hn = (1.f - ig) * nn + ig * hidden[idx];
  out[12800 + idx] = hn;
  hnewbf[idx] = f2bf(hn);
}

// ---- K5/K6: dst = relu(A @ WT + bias) (bf16); cols split by y ----
__global__ __launch_bounds__(256) void k_mlp(
    const unsigned short* __restrict__ A, const unsigned short* __restrict__ WT,
    const float* __restrict__ bias, unsigned short* __restrict__ dst) {
  __shared__ alignas(16) unsigned char smem[32768];
  int tid = threadIdx.x, lane = tid & 63, wv = tid >> 6;
  int mt = blockIdx.x, y = blockIdx.y;
  stage_bf16_64(A + (size_t)mt * 64 * 256, smem, tid);
  __syncthreads();
  int nb = y * 64 + wv * 16;
  f32x4 zz = {0.f, 0.f, 0.f, 0.f};
  f32x4 acc[4][1];
#pragma unroll
  for (int m = 0; m < 4; ++m) acc[m][0] = zz;
  gemm_tile<4, 1>(smem, WT, nb, lane, acc);
  unsigned short* d = dst + (size_t)mt * 64 * 256;
  int li = lane & 15, lg = lane >> 4;
  int col = nb + li;
  float bv = bias[col];
#pragma unroll
  for (int m = 0; m < 4; ++m)
#pragma unroll
    for (int q = 0; q < 4; ++q) {
      float v = fmaxf(acc[m][0][q] + bv, 0.f);
      d[(m * 16 + lg * 4 + q) * 256 + col] = f2bf(v);
    }
}

// ---- K7: pred = inputs + pred2 @ Wo3 + bo3 ----
__global__ __launch_bounds__(64) void k7_out(
    const unsigned short* __restrict__ pred2, const float* __restrict__ Wo3,
    const float* __restrict__ bo3, const float* __restrict__ inputs, float* __restrict__ out) {
  int row = blockIdx.x, lane = threadIdx.x;
  u16x4 p = *reinterpret_cast<const u16x4*>(pred2 + (size_t)row * 256 + lane * 4);
  float s0 = 0.f, s1 = 0.f, s2 = 0.f, s3 = 0.f;
#pragma unroll
  for (int j = 0; j < 4; ++j) {
    float pv = bf2f(p[j]);
    const float* wr = Wo3 + (lane * 4 + j) * 4;
    s0 += pv * wr[0]; s1 += pv * wr[1]; s2 += pv * wr[2]; s3 += pv * wr[3];
  }
#pragma unroll
  for (int off = 32; off >= 1; off >>= 1) {
    s0 += __shfl_xor(s0, off); s1 += __shfl_xor(s1, off);
    s2 += __shfl_xor(s2, off); s3 += __shfl_xor(s3, off);
  }
  if (lane == 0) {
    out[row * 4 + 0] = inputs[row * 4 + 0] + s0 + bo3[0];
    out[row * 4 + 1] = inputs[row * 4 + 1] + s1 + bo3[1];
    out[row * 4 + 2] = inputs[row * 4 + 2] + s2 + bo3[2];
    out[row * 4 + 3] = inputs[row * 4 + 3] + s3 + bo3[3];
  }
}

extern "C" void kernel_launch(void* const* d_in, const int* in_sizes, int n_in,
                              void* d_out, int out_size, void* d_ws, size_t ws_size,
                              hipStream_t stream) {
  const float* inputs = (const float*)d_in[0];
  const float* hidden = (const float*)d_in[1];
  const float* edges  = (const float*)d_in[2];
  const float* msg_W1 = (const float*)d_in[3];
  const float* msg_b1 = (const float*)d_in[4];
  const float* msg_W2 = (const float*)d_in[5];
  const float* msg_b2 = (const float*)d_in[6];
  const float* Whr = (const float*)d_in[7];
  const float* Whi = (const float*)d_in[8];
  const float* Whh = (const float*)d_in[9];
  const float* Wir = (const float*)d_in[10];
  const float* bir = (const float*)d_in[11];
  const float* Wii = (const float*)d_in[12];
  const float* bii = (const float*)d_in[13];
  const float* Win = (const float*)d_in[14];
  const float* bin_ = (const float*)d_in[15];
  const float* Wo1 = (const float*)d_in[16];
  const float* bo1 = (const float*)d_in[17];
  const float* Wo2 = (const float*)d_in[18];
  const float* bo2 = (const float*)d_in[19];
  const float* Wo3 = (const float*)d_in[20];
  const float* bo3 = (const float*)d_in[21];
  float* out = (float*)d_out;

  char* ws = (char*)d_ws;
  size_t off = 0;
  auto take = [&](size_t bytes) -> char* {
    char* p = ws + off;
    off += (bytes + 511) & ~(size_t)511;
    return p;
  };
  unsigned short* W1aT = (unsigned short*)take(196608 * 2);
  unsigned short* W1bT = (unsigned short*)take(196608 * 2);
  unsigned short* W2Q  = (unsigned short*)take(196608);      // fp8 [3][256][256]
  unsigned short* WhT  = (unsigned short*)take(327680 * 2);  // WhrT|WhiT|WhhT|Wo1T|Wo2T
  unsigned short* Ha   = (unsigned short*)take(2457600 * 2); // [3][3200][256]
  unsigned short* Hb   = (unsigned short*)take(2457600 * 2);
  float* pagg = (float*)take(3 * 819200 * 4);                // [3][3200][256] partial agg
  unsigned char* m1G = (unsigned char*)take((size_t)3200 * 28672); // one ti slice, 91.75MB
  float* Xpre = (float*)take(2457600 * 4);                   // [3200][768]
  float* RIH  = (float*)take(2457600 * 4);                   // [3][3200][256]
  unsigned short* hnewbf = (unsigned short*)take(819200 * 2);
  unsigned short* pred1  = (unsigned short*)take(819200 * 2);
  unsigned short* pred2  = (unsigned short*)take(819200 * 2);

  kpre<<<12800, 256, 0, stream>>>(msg_W1, msg_W2, Whr, Whi, Whh, Wo1, Wo2,
                                  inputs, Wir, bir, Wii, bii, Win, bin_,
                                  W1aT, W1bT, WhT, W2Q, Xpre);
  k1_nodepre<<<dim3(50, 6, 2), 256, 0, stream>>>(hidden, msg_b1, W1aT, W1bT, Ha, Hb);
  for (int ti = 0; ti < 3; ++ti) {
    k2a_build<<<3200, 256, 0, stream>>>(Ha, Hb, m1G, ti);
    k2b_gemm<<<3200, 256, 0, stream>>>(edges, msg_b2, m1G,
                                       (const unsigned char*)W2Q, pagg, ti);
  }
  k3_gemm<<<dim3(50, 3, 2), 256, 0, stream>>>(pagg, WhT, RIH);
  k4_gru<<<3200, 256, 0, stream>>>(Xpre, RIH, hidden, out, hnewbf);
  k_mlp<<<dim3(50, 4), 256, 0, stream>>>(hnewbf, WhT + 196608, bo1, pred1);
  k_mlp<<<dim3(50, 4), 256, 0, stream>>>(pred1, WhT + 262144, bo2, pred2);
  k7_out<<<3200, 64, 0, stream>>>(pred2, Wo3, bo3, inputs, out);
}

// Round 20
// 329.517 us; speedup vs baseline: 1.4151x; 1.0133x over previous
//
#include <hip/hip_runtime.h>
#include <hip/hip_bf16.h>

// DNRI step: B=32, N=100, D=4, H=256, K=4 (skip type 0), E=9900.
// R19: R18 + k3/k4 fusion (k34): the GRU elementwise pass runs in k3's
// epilogue (3 Wh GEMMs via y-loop, gates in-register) -> one launch fewer,
// RIH buffer + 20MB round trip eliminated. k2 chain frozen (R17 form).

typedef __attribute__((ext_vector_type(4))) float f32x4;
typedef __attribute__((ext_vector_type(8))) short s16x8;
typedef __attribute__((ext_vector_type(4))) unsigned short u16x4;
typedef __attribute__((ext_vector_type(4))) unsigned int u32x4;
typedef __attribute__((ext_vector_type(2))) unsigned int u32x2;

#define DEV static __device__ __forceinline__

DEV unsigned short f2bf(float f) {
  unsigned int u = __builtin_bit_cast(unsigned int, f);
  u += 0x7fffu + ((u >> 16) & 1u);   // RNE
  return (unsigned short)(u >> 16);
}
DEV float bf2f(unsigned short h) {
  unsigned int u = ((unsigned int)h) << 16;
  return __builtin_bit_cast(float, u);
}
DEV float bflo(unsigned int u) { return __builtin_bit_cast(float, u << 16); }
DEV float bfhi(unsigned int u) { return __builtin_bit_cast(float, u & 0xffff0000u); }
DEV float exp2_fast(float x) { return __builtin_amdgcn_exp2f(x); }
DEV float tanh_fast(float x) {
  float e = exp2_fast(x * 2.885390082f);            // exp(2x)
  return 1.f - 2.f * __builtin_amdgcn_rcpf(e + 1.f);
}
DEV float sigmoid_fast(float x) {
  return __builtin_amdgcn_rcpf(1.f + exp2_fast(-1.442695041f * x));
}
DEV unsigned int pk_fp8x4(float a, float b, float c, float d) {
  int v = __builtin_amdgcn_cvt_pk_fp8_f32(a, b, 0, false);   // bytes 0,1
  v = __builtin_amdgcn_cvt_pk_fp8_f32(c, d, v, true);        // bytes 2,3
  return (unsigned int)v;
}
// async global->LDS DMA, 16B per lane; LDS dest = base + lane*16 (wave-uniform base)
DEV void gload_lds16(const unsigned char* g, unsigned char* l) {
  __builtin_amdgcn_global_load_lds(
      (const __attribute__((address_space(1))) void*)g,
      (__attribute__((address_space(3))) void*)l, 16, 0, 0);
}

// ---- LDS staging: 64 rows x 256 bf16, XOR-swizzled ----
DEV void stage_bf16_64(const unsigned short* __restrict__ src, unsigned char* smem, int tid) {
#pragma unroll
  for (int j = 0; j < 8; ++j) {
    int c = tid + 256 * j;
    int s = c >> 5, hc = c & 31;
    s16x8 v = *reinterpret_cast<const s16x8*>(src + s * 256 + hc * 8);
    int byte = (s * 512 + hc * 16) ^ ((s & 7) << 4);
    *reinterpret_cast<s16x8*>(smem + byte) = v;
  }
}
DEV void stage_f32_64(const float* __restrict__ src, unsigned char* smem, int tid) {
#pragma unroll
  for (int j = 0; j < 8; ++j) {
    int c = tid + 256 * j;
    int s = c >> 5, hc = c & 31;
    const float* p = src + s * 256 + hc * 8;
    f32x4 v0 = *reinterpret_cast<const f32x4*>(p);
    f32x4 v1 = *reinterpret_cast<const f32x4*>(p + 4);
    s16x8 o;
#pragma unroll
    for (int i = 0; i < 4; ++i) { o[i] = (short)f2bf(v0[i]); o[4 + i] = (short)f2bf(v1[i]); }
    int byte = (s * 512 + hc * 16) ^ ((s & 7) << 4);
    *reinterpret_cast<s16x8*>(smem + byte) = o;
  }
}
// staging that sums three f32 partial buffers -> bf16 swizzled LDS
DEV void stage_sum3_f32(const float* __restrict__ sa, const float* __restrict__ sb,
                        const float* __restrict__ sc, unsigned char* smem, int tid) {
#pragma unroll
  for (int j = 0; j < 8; ++j) {
    int c = tid + 256 * j;
    int s = c >> 5, hc = c & 31;
    int o4 = s * 256 + hc * 8;
    f32x4 a0 = *reinterpret_cast<const f32x4*>(sa + o4);
    f32x4 a1 = *reinterpret_cast<const f32x4*>(sa + o4 + 4);
    f32x4 b0 = *reinterpret_cast<const f32x4*>(sb + o4);
    f32x4 b1 = *reinterpret_cast<const f32x4*>(sb + o4 + 4);
    f32x4 c0 = *reinterpret_cast<const f32x4*>(sc + o4);
    f32x4 c1 = *reinterpret_cast<const f32x4*>(sc + o4 + 4);
    s16x8 o;
#pragma unroll
    for (int i = 0; i < 4; ++i) {
      o[i] = (short)f2bf(a0[i] + b0[i] + c0[i]);
      o[4 + i] = (short)f2bf(a1[i] + b1[i] + c1[i]);
    }
    int byte = (s * 512 + hc * 16) ^ ((s & 7) << 4);
    *reinterpret_cast<s16x8*>(smem + byte) = o;
  }
}

// ---- bf16 MFMA tile helper: A (MF*16 x 256) in swizzled LDS, B^T [n][k] bf16
// in global; wave computes NF 16-col fragments starting at col nb. ----
template<int MF, int NF>
DEV void gemm_tile(const unsigned char* smemA, const unsigned short* __restrict__ B,
                   int nb, int lane, f32x4 acc[MF][NF]) {
  int li = lane & 15, lg = lane >> 4;
#pragma unroll
  for (int kk = 0; kk < 8; ++kk) {
    int kb = kk * 32 + lg * 8;
    s16x8 a[MF];
#pragma unroll
    for (int m = 0; m < MF; ++m) {
      int row = m * 16 + li;
      int byte = (row * 512 + kb * 2) ^ ((row & 7) << 4);
      a[m] = *reinterpret_cast<const s16x8*>(smemA + byte);
    }
#pragma unroll
    for (int n = 0; n < NF; ++n) {
      int col = nb + n * 16 + li;
      s16x8 bf = *reinterpret_cast<const s16x8*>(B + col * 256 + kb);
#pragma unroll
      for (int m = 0; m < MF; ++m)
        acc[m][n] = __builtin_amdgcn_mfma_f32_16x16x32_bf16(a[m], bf, acc[m][n], 0, 0, 0);
    }
  }
}

// ---- KPRE: merged k0_pack + k0_quant + k_xpre ----
__global__ __launch_bounds__(256) void kpre(
    const float* __restrict__ msg_W1, const float* __restrict__ msg_W2,
    const float* __restrict__ Whr, const float* __restrict__ Whi, const float* __restrict__ Whh,
    const float* __restrict__ Wo1, const float* __restrict__ Wo2,
    const float* __restrict__ inputs, const float* __restrict__ Wir, const float* __restrict__ bir,
    const float* __restrict__ Wii, const float* __restrict__ bii,
    const float* __restrict__ Win, const float* __restrict__ bin_,
    unsigned short* __restrict__ W1aT, unsigned short* __restrict__ W1bT,
    unsigned short* __restrict__ WhT, unsigned short* __restrict__ W2Q,
    float* __restrict__ Xpre) {
  int blk = blockIdx.x, tid = threadIdx.x;
  if (blk < 2816) {                    // --- pack ---
    int g = blk * 256 + tid;
    if (g < 196608) {                  // W1aT[ti][n][k] = msg_W1[ti+1][k][n]
      int ti = g >> 16, rem = g & 65535, n = rem >> 8, k = rem & 255;
      W1aT[g] = f2bf(msg_W1[((ti + 1) * 512 + k) * 256 + n]);
    } else if (g < 393216) {           // W1bT[ti][n][k] = msg_W1[ti+1][256+k][n]
      int h = g - 196608; int ti = h >> 16, rem = h & 65535, n = rem >> 8, k = rem & 255;
      W1bT[h] = f2bf(msg_W1[((ti + 1) * 512 + 256 + k) * 256 + n]);
    } else if (g < 720896) {           // WhT: {Whr,Whi,Whh,Wo1,Wo2}^T
      int h = g - 393216; int mi = h >> 16, rem = h & 65535, n = rem >> 8, k = rem & 255;
      const float* s = mi == 0 ? Whr : mi == 1 ? Whi : mi == 2 ? Whh : mi == 3 ? Wo1 : Wo2;
      WhT[h] = f2bf(s[k * 256 + n]);
    }
  } else if (blk < 3200) {             // --- quant W2 -> fp8 [ti][col][k] ---
    int g = (blk - 2816) * 256 + tid;  // 98304 = 3*256*128
    int ti = g >> 15, rem = g & 32767, col = rem >> 7, k2 = rem & 127;
    int k = k2 * 2;
    const float* src = msg_W2 + (size_t)(ti + 1) * 65536;
    float a = src[k * 256 + col], b = src[(k + 1) * 256 + col];
    int v = __builtin_amdgcn_cvt_pk_fp8_f32(a, b, 0, false);
    W2Q[g] = (unsigned short)(v & 0xffff);
  } else {                             // --- xpre ---
    int g = (blk - 3200) * 256 + tid;  // 3200*768 exact
    int row = g / 768, c = g % 768, which = c >> 8, col = c & 255;
    const float* W = which == 0 ? Wir : which == 1 ? Wii : Win;
    const float* bb = which == 0 ? bir : which == 1 ? bii : bin_;
    const float* inp = inputs + row * 4;
    float s = bb[col];
#pragma unroll
    for (int d = 0; d < 4; ++d) s += inp[d] * W[d * 256 + col];
    Xpre[g] = s;
  }
}

// ---- K1: Ha[ti] = hidden@W1a+b1 (bf16), Hb[ti] = hidden@W1b; cols split by z ----
__global__ __launch_bounds__(256) void k1_nodepre(
    const float* __restrict__ hidden, const float* __restrict__ msg_b1,
    const unsigned short* __restrict__ W1aT, const unsigned short* __restrict__ W1bT,
    unsigned short* __restrict__ Ha, unsigned short* __restrict__ Hb) {
  __shared__ alignas(16) unsigned char smem[32768];
  int tid = threadIdx.x, lane = tid & 63, wv = tid >> 6;
  int mt = blockIdx.x, g = blockIdx.y, z = blockIdx.z;
  stage_f32_64(hidden + (size_t)mt * 64 * 256, smem, tid);
  __syncthreads();
  int ti = g < 3 ? g : g - 3;
  const unsigned short* Bp = (g < 3 ? W1aT : W1bT) + ti * 65536;
  int nb = z * 128 + wv * 32;
  f32x4 zz = {0.f, 0.f, 0.f, 0.f};
  f32x4 acc[4][2];
#pragma unroll
  for (int m = 0; m < 4; ++m) { acc[m][0] = zz; acc[m][1] = zz; }
  gemm_tile<4, 2>(smem, Bp, nb, lane, acc);
  unsigned short* dst = (g < 3 ? Ha : Hb) + (size_t)ti * 819200 + (size_t)mt * 64 * 256;
  int li = lane & 15, lg = lane >> 4;
#pragma unroll
  for (int n = 0; n < 2; ++n) {
    int col = nb + n * 16 + li;
    float bias = g < 3 ? msg_b1[(ti + 1) * 256 + col] : 0.f;
#pragma unroll
    for (int m = 0; m < 4; ++m)
#pragma unroll
      for (int q = 0; q < 4; ++q) {
        int row = m * 16 + lg * 4 + q;
        dst[row * 256 + col] = f2bf(acc[m][n][q] + bias);
      }
  }
}

// ---- K2a: streaming build of one type-slice of m1 (fp8, PRE-SWIZZLED) ----
__global__ __launch_bounds__(256) void k2a_build(
    const unsigned short* __restrict__ Ha, const unsigned short* __restrict__ Hb,
    unsigned char* __restrict__ m1G, int ti) {
  int tid = threadIdx.x;
  int bid0 = blockIdx.x;
  int bid = (bid0 & 7) * 400 + (bid0 >> 3);   // XCD-contiguous (3200 = 8*400)
  int b = bid / 100, r = bid % 100;
  int hc = tid & 31, srow0 = tid >> 5;

  u32x4 hau = *reinterpret_cast<const u32x4*>(
      Ha + ((size_t)ti * 3200 + b * 100 + r) * 256 + hc * 8);
  float ha_f[8];
#pragma unroll
  for (int i = 0; i < 4; ++i) { ha_f[2 * i] = bflo(hau[i]); ha_f[2 * i + 1] = bfhi(hau[i]); }
  const unsigned short* HbB = Hb + ((size_t)ti * 3200 + b * 100) * 256;
  unsigned char* dst = m1G + (size_t)bid * 28672;
#pragma unroll
  for (int j = 0; j < 14; ++j) {
    int s = srow0 + 8 * j;
    u32x2 o = {0u, 0u};
    if (s < 99) {
      int snode = s + (s >= r ? 1 : 0);
      u32x4 hb = *reinterpret_cast<const u32x4*>(HbB + snode * 256 + hc * 8);
      float t[8];
#pragma unroll
      for (int i = 0; i < 4; ++i) {
        t[2 * i] = tanh_fast(ha_f[2 * i] + bflo(hb[i]));
        t[2 * i + 1] = tanh_fast(ha_f[2 * i + 1] + bfhi(hb[i]));
      }
      o[0] = pk_fp8x4(t[0], t[1], t[2], t[3]);
      o[1] = pk_fp8x4(t[4], t[5], t[6], t[7]);
    }
    int byte = (s * 256 + hc * 8) ^ ((s & 7) << 4);   // pre-swizzle on global write
    *reinterpret_cast<u32x2*>(dst + byte) = o;
  }
}

// ---- K2b: DMA-stage m1 slice -> LDS (linear dest), fp8 GEMM, tanh epilogue ----
// grid 3200, 1 tile/block.
// LDS: m1 fp8 image @0 (28672) | w [112] f32 @28672 | agg [256] f32 @29120
__global__ __launch_bounds__(256) void k2b_gemm(
    const float* __restrict__ edges, const float* __restrict__ msg_b2,
    const unsigned char* __restrict__ m1G, const unsigned char* __restrict__ W2Q,
    float* __restrict__ pagg, int ti) {
  __shared__ alignas(16) unsigned char smem[30144];
  float* w_s = (float*)(smem + 28672);
  float* agg_s = (float*)(smem + 29120);
  int tid = threadIdx.x, lane = tid & 63, wv = tid >> 6;
  int li = lane & 15, lg = lane >> 4;
  int bid0 = blockIdx.x;
  int bid = (bid0 & 7) * 400 + (bid0 >> 3);
  int b = bid / 100, r = bid % 100;

  // stage tile via async DMA (linear LDS dest; source pre-swizzled by k2a)
  const unsigned char* src = m1G + (size_t)bid * 28672;
#pragma unroll
  for (int j = 0; j < 7; ++j) {
    int chunk = wv * 7 + j;
    gload_lds16(src + chunk * 1024 + lane * 16, smem + chunk * 1024);
  }
  // edge weights for this type (analytic dense edge index) — overlaps DMA
  {
    float w0 = 0.f;
    if (tid < 99) {
      int snode = tid + (tid >= r ? 1 : 0);
      int e = snode * 99 + r - (r > snode ? 1 : 0);
      w0 = edges[(size_t)(b * 9900 + e) * 4 + (ti + 1)] * (1.f / 297.f);
    }
    if (tid < 112) w_s[tid] = w0;
  }
  __syncthreads();   // drains DMA (vmcnt) + w_s visible

  float b2r[4];
#pragma unroll
  for (int n = 0; n < 4; ++n)
    b2r[n] = msg_b2[(ti + 1) * 256 + wv * 64 + n * 16 + li];

  float aggacc[4] = {0.f, 0.f, 0.f, 0.f};
  f32x4 zz = {0.f, 0.f, 0.f, 0.f};
  const unsigned char* Bq = W2Q + (size_t)ti * 65536;
#pragma unroll
  for (int p = 0; p < 2; ++p) {
    f32x4 acc[7][2];
#pragma unroll
    for (int m = 0; m < 7; ++m) { acc[m][0] = zz; acc[m][1] = zz; }
#pragma unroll
    for (int kk = 0; kk < 8; ++kk) {
      int ko = kk * 32 + lg * 8;
      long a[7];
#pragma unroll
      for (int m = 0; m < 7; ++m) {
        int row = m * 16 + li;
        int byte = (row * 256 + ko) ^ ((row & 7) << 4);
        a[m] = *reinterpret_cast<const long*>(smem + byte);
      }
#pragma unroll
      for (int n = 0; n < 2; ++n) {
        int col = wv * 64 + p * 32 + n * 16 + li;
        long bq = *reinterpret_cast<const long*>(Bq + col * 256 + ko);
#pragma unroll
        for (int m = 0; m < 7; ++m)
          acc[m][n] = __builtin_amdgcn_mfma_f32_16x16x32_fp8_fp8(a[m], bq, acc[m][n], 0, 0, 0);
      }
    }
    // epilogue for this pass (reg + broadcast-LDS only)
#pragma unroll
    for (int n = 0; n < 2; ++n) {
      float b2v = b2r[p * 2 + n];
      float pa = 0.f;
#pragma unroll
      for (int m = 0; m < 7; ++m) {
        f32x4 wf = *reinterpret_cast<const f32x4*>(w_s + m * 16 + lg * 4);
#pragma unroll
        for (int q = 0; q < 4; ++q)
          pa += tanh_fast(acc[m][n][q] + b2v) * wf[q];
      }
      aggacc[p * 2 + n] += pa;
    }
  }

  // reduce row-groups (C layout: col=lane&15, row=(lane>>4)*4+q)
#pragma unroll
  for (int n = 0; n < 4; ++n) {
    float v = aggacc[n];
    v += __shfl_xor(v, 16);
    v += __shfl_xor(v, 32);
    if (lane < 16) agg_s[wv * 64 + n * 16 + lane] = v;
  }
  __syncthreads();
  pagg[(size_t)ti * 819200 + (size_t)bid * 256 + tid] = agg_s[tid];
}

// ---- K34: fused k3 + k4. Block (mt, z): stage summed agg tile, run the 3
// Wh GEMMs (y-loop), apply GRU gates in-register, write out + hnewbf. ----
__global__ __launch_bounds__(256) void k34_gemm_gru(
    const float* __restrict__ pagg, const unsigned short* __restrict__ WhT,
    const float* __restrict__ Xpre, const float* __restrict__ hidden,
    float* __restrict__ out, unsigned short* __restrict__ hnewbf) {
  __shared__ alignas(16) unsigned char smem[32768];
  int tid = threadIdx.x, lane = tid & 63, wv = tid >> 6;
  int mt = blockIdx.x, z = blockIdx.y;   // z in 0..3 -> 64-col quarter
  size_t base = (size_t)mt * 64 * 256;
  stage_sum3_f32(pagg + base, pagg + 819200 + base, pagg + 1638400 + base, smem, tid);
  __syncthreads();
  int nb = z * 64 + wv * 16;
  f32x4 zz = {0.f, 0.f, 0.f, 0.f};
  f32x4 accR[4][1], accI[4][1], accH[4][1];
#pragma unroll
  for (int m = 0; m < 4; ++m) { accR[m][0] = zz; accI[m][0] = zz; accH[m][0] = zz; }
  gemm_tile<4, 1>(smem, WhT, nb, lane, accR);            // agg @ Whr
  gemm_tile<4, 1>(smem, WhT + 65536, nb, lane, accI);    // agg @ Whi
  gemm_tile<4, 1>(smem, WhT + 131072, nb, lane, accH);   // agg @ Whh
  int li = lane & 15, lg = lane >> 4;
  int col = nb + li;
#pragma unroll
  for (int m = 0; m < 4; ++m)
#pragma unroll
    for (int q = 0; q < 4; ++q) {
      int row = mt * 64 + m * 16 + lg * 4 + q;
      int idx = row * 256 + col;
      float xr = Xpre[row * 768 + col];
      float xi = Xpre[row * 768 + 256 + col];
      float xn = Xpre[row * 768 + 512 + col];
      float rr = sigmoid_fast(xr + accR[m][0][q]);
      float ig = sigmoid_fast(xi + accI[m][0][q]);
      float nn = tanh_fast(xn + rr * accH[m][0][q]);
      float hn = (1.f - ig) * nn + ig * hidden[idx];
      out[12800 + idx] = hn;
      hnewbf[idx] = f2bf(hn);
    }
}

// ---- K5/K6: dst = relu(A @ WT + bias) (bf16); cols split by y ----
__global__ __launch_bounds__(256) void k_mlp(
    const unsigned short* __restrict__ A, const unsigned short* __restrict__ WT,
    const float* __restrict__ bias, unsigned short* __restrict__ dst) {
  __shared__ alignas(16) unsigned char smem[32768];
  int tid = threadIdx.x, lane = tid & 63, wv = tid >> 6;
  int mt = blockIdx.x, y = blockIdx.y;
  stage_bf16_64(A + (size_t)mt * 64 * 256, smem, tid);
  __syncthreads();
  int nb = y * 64 + wv * 16;
  f32x4 zz = {0.f, 0.f, 0.f, 0.f};
  f32x4 acc[4][1];
#pragma unroll
  for (int m = 0; m < 4; ++m) acc[m][0] = zz;
  gemm_tile<4, 1>(smem, WT, nb, lane, acc);
  unsigned short* d = dst + (size_t)mt * 64 * 256;
  int li = lane & 15, lg = lane >> 4;
  int col = nb + li;
  float bv = bias[col];
#pragma unroll
  for (int m = 0; m < 4; ++m)
#pragma unroll
    for (int q = 0; q < 4; ++q) {
      float v = fmaxf(acc[m][0][q] + bv, 0.f);
      d[(m * 16 + lg * 4 + q) * 256 + col] = f2bf(v);
    }
}

// ---- K7: pred = inputs + pred2 @ Wo3 + bo3 ----
__global__ __launch_bounds__(64) void k7_out(
    const unsigned short* __restrict__ pred2, const float* __restrict__ Wo3,
    const float* __restrict__ bo3, const float* __restrict__ inputs, float* __restrict__ out) {
  int row = blockIdx.x, lane = threadIdx.x;
  u16x4 p = *reinterpret_cast<const u16x4*>(pred2 + (size_t)row * 256 + lane * 4);
  float s0 = 0.f, s1 = 0.f, s2 = 0.f, s3 = 0.f;
#pragma unroll
  for (int j = 0; j < 4; ++j) {
    float pv = bf2f(p[j]);
    const float* wr = Wo3 + (lane * 4 + j) * 4;
    s0 += pv * wr[0]; s1 += pv * wr[1]; s2 += pv * wr[2]; s3 += pv * wr[3];
  }
#pragma unroll
  for (int off = 32; off >= 1; off >>= 1) {
    s0 += __shfl_xor(s0, off); s1 += __shfl_xor(s1, off);
    s2 += __shfl_xor(s2, off); s3 += __shfl_xor(s3, off);
  }
  if (lane == 0) {
    out[row * 4 + 0] = inputs[row * 4 + 0] + s0 + bo3[0];
    out[row * 4 + 1] = inputs[row * 4 + 1] + s1 + bo3[1];
    out[row * 4 + 2] = inputs[row * 4 + 2] + s2 + bo3[2];
    out[row * 4 + 3] = inputs[row * 4 + 3] + s3 + bo3[3];
  }
}

extern "C" void kernel_launch(void* const* d_in, const int* in_sizes, int n_in,
                              void* d_out, int out_size, void* d_ws, size_t ws_size,
                              hipStream_t stream) {
  const float* inputs = (const float*)d_in[0];
  const float* hidden = (const float*)d_in[1];
  const float* edges  = (const float*)d_in[2];
  const float* msg_W1 = (const float*)d_in[3];
  const float* msg_b1 = (const float*)d_in[4];
  const float* msg_W2 = (const float*)d_in[5];
  const float* msg_b2 = (const float*)d_in[6];
  const float* Whr = (const float*)d_in[7];
  const float* Whi = (const float*)d_in[8];
  const float* Whh = (const float*)d_in[9];
  const float* Wir = (const float*)d_in[10];
  const float* bir = (const float*)d_in[11];
  const float* Wii = (const float*)d_in[12];
  const float* bii = (const float*)d_in[13];
  const float* Win = (const float*)d_in[14];
  const float* bin_ = (const float*)d_in[15];
  const float* Wo1 = (const float*)d_in[16];
  const float* bo1 = (const float*)d_in[17];
  const float* Wo2 = (const float*)d_in[18];
  const float* bo2 = (const float*)d_in[19];
  const float* Wo3 = (const float*)d_in[20];
  const float* bo3 = (const float*)d_in[21];
  float* out = (float*)d_out;

  char* ws = (char*)d_ws;
  size_t off = 0;
  auto take = [&](size_t bytes) -> char* {
    char* p = ws + off;
    off += (bytes + 511) & ~(size_t)511;
    return p;
  };
  unsigned short* W1aT = (unsigned short*)take(196608 * 2);
  unsigned short* W1bT = (unsigned short*)take(196608 * 2);
  unsigned short* W2Q  = (unsigned short*)take(196608);      // fp8 [3][256][256]
  unsigned short* WhT  = (unsigned short*)take(327680 * 2);  // WhrT|WhiT|WhhT|Wo1T|Wo2T
  unsigned short* Ha   = (unsigned short*)take(2457600 * 2); // [3][3200][256]
  unsigned short* Hb   = (unsigned short*)take(2457600 * 2);
  float* pagg = (float*)take(3 * 819200 * 4);                // [3][3200][256] partial agg
  unsigned char* m1G = (unsigned char*)take((size_t)3200 * 28672); // one ti slice, 91.75MB
  float* Xpre = (float*)take(2457600 * 4);                   // [3200][768]
  unsigned short* hnewbf = (unsigned short*)take(819200 * 2);
  unsigned short* pred1  = (unsigned short*)take(819200 * 2);
  unsigned short* pred2  = (unsigned short*)take(819200 * 2);

  kpre<<<12800, 256, 0, stream>>>(msg_W1, msg_W2, Whr, Whi, Whh, Wo1, Wo2,
                                  inputs, Wir, bir, Wii, bii, Win, bin_,
                                  W1aT, W1bT, WhT, W2Q, Xpre);
  k1_nodepre<<<dim3(50, 6, 2), 256, 0, stream>>>(hidden, msg_b1, W1aT, W1bT, Ha, Hb);
  for (int ti = 0; ti < 3; ++ti) {
    k2a_build<<<3200, 256, 0, stream>>>(Ha, Hb, m1G, ti);
    k2b_gemm<<<3200, 256, 0, stream>>>(edges, msg_b2, m1G,
                                       (const unsigned char*)W2Q, pagg, ti);
  }
  k34_gemm_gru<<<dim3(50, 4), 256, 0, stream>>>(pagg, WhT, Xpre, hidden, out, hnewbf);
  k_mlp<<<dim3(50, 4), 256, 0, stream>>>(hnewbf, WhT + 196608, bo1, pred1);
  k_mlp<<<dim3(50, 4), 256, 0, stream>>>(pred1, WhT + 262144, bo2, pred2);
  k7_out<<<3200, 64, 0, stream>>>(pred2, Wo3, bo3, inputs, out);
}